// Round 2
// baseline (486.539 us; speedup 1.0000x reference)
//
#include <hip/hip_runtime.h>
#include <hip/hip_fp16.h>
#include <math.h>

constexpr int NN = 50000;
constexpr int NE = 800000;
constexpr int NEP = NE + NN;             // edges + self-loops
constexpr int CAP = 96;                  // bucket capacity (slot 0 = implicit self-loop)
constexpr int SCAT2_B = (NE / 4 + 255) / 256;  // 782 blocks, 4 edges/thread
constexpr int PACK_B = 26;                     // 6656 pack threads (W2..Wf1)
constexpr int NT = (NN + 63) / 64;             // 782 gemm tiles

typedef _Float16 half8_t __attribute__((ext_vector_type(8)));
typedef float    f32x4_t __attribute__((ext_vector_type(4)));

__device__ __forceinline__ float lrelu02(float x) { return x > 0.f ? x : 0.2f * x; }
__device__ __forceinline__ float eluf(float x)    { return x > 0.f ? x : (__expf(x) - 1.f); }
__device__ __forceinline__ float pick4(float4 q, int hd) {
  return (hd == 0) ? q.x : (hd == 1) ? q.y : (hd == 2) ? q.z : q.w;
}

// ---------------- W pre-pack into MFMA B-fragment order ----------------

__device__ __forceinline__ void pack_w_one(const float* __restrict__ W,
                                           __half* __restrict__ Wp,
                                           int M, int tid, int total) {
  if (tid >= total) return;
  int CT = M >> 4;
  int l = tid & 63;
  int c = (tid >> 6) % CT;
  int kc = (tid >> 6) / CT;
  int n = l & 15, q = l >> 4;
  __half* dst = Wp + (size_t)tid * 8;
  const float* src = W + (size_t)(kc * 32 + q * 8) * M + c * 16 + n;
  #pragma unroll
  for (int j = 0; j < 8; j++) dst[j] = __float2half_rn(src[j * M]);
}

// ---------------- fused alpha epilogue ----------

template<int M, int C, int CT>
__device__ __forceinline__ void alpha_epilogue(const f32x4_t* acc,
    const float* __restrict__ a_src, const float* __restrict__ a_dst,
    int row_base, int m, float* __restrict__ as_out, float* __restrict__ ad_out) {
  float aS[CT], aD[CT];
  #pragma unroll
  for (int c = 0; c < CT; c++) { aS[c] = a_src[c * 16 + m]; aD[c] = a_dst[c * 16 + m]; }

  if constexpr (C == 8) {
    #pragma unroll
    for (int r = 0; r < 4; r++) {
      float p0 = acc[0][r] * aS[0], p1 = acc[1][r] * aS[1];
      float q0 = acc[0][r] * aD[0], q1 = acc[1][r] * aD[1];
      #pragma unroll
      for (int off = 1; off < 8; off <<= 1) {
        p0 += __shfl_xor(p0, off); p1 += __shfl_xor(p1, off);
        q0 += __shfl_xor(q0, off); q1 += __shfl_xor(q1, off);
      }
      int row = row_base + r;
      if ((m & 7) == 0 && row < NN) {
        int hb = m >> 3;
        as_out[row * 4 + hb]     = p0;
        as_out[row * 4 + 2 + hb] = p1;
        ad_out[row * 4 + hb]     = q0;
        ad_out[row * 4 + 2 + hb] = q1;
      }
    }
  } else {
    constexpr int FPH = C / 16;
    #pragma unroll
    for (int r = 0; r < 4; r++) {
      float bs[4] = {0.f, 0.f, 0.f, 0.f}, bd[4] = {0.f, 0.f, 0.f, 0.f};
      #pragma unroll
      for (int c = 0; c < CT; c++) {
        int hd = c / FPH;
        bs[hd] += acc[c][r] * aS[c];
        bd[hd] += acc[c][r] * aD[c];
      }
      #pragma unroll
      for (int off = 1; off < 16; off <<= 1)
        #pragma unroll
        for (int h = 0; h < 4; h++) {
          bs[h] += __shfl_xor(bs[h], off);
          bd[h] += __shfl_xor(bd[h], off);
        }
      int row = row_base + r;
      if (m < 4 && row < NN) {
        float vs = (m == 0) ? bs[0] : (m == 1) ? bs[1] : (m == 2) ? bs[2] : bs[3];
        float vd = (m == 0) ? bd[0] : (m == 1) ? bd[1] : (m == 2) ? bd[2] : bd[3];
        as_out[row * 4 + m] = vs;
        ad_out[row * 4 + m] = vd;
      }
    }
  }
}

// ---------------- merged front kernel: gemm1 | scatter | pack(W2..Wf1) ------
// gemm1 blocks come FIRST so MFMA work starts immediately; the latency-bound
// scatter blocks fill in around it. Self-loops are implicit (slot 0 == dst),
// so the scatter only covers the NE real edges, 4 per thread for ILP.

__global__ __launch_bounds__(256) void front_kernel(
    const int* __restrict__ edge_src, const int* __restrict__ edge_dst,
    int* __restrict__ count, int* __restrict__ csr_src,
    const float* __restrict__ W1,
    const float* __restrict__ W2, __half* __restrict__ Wp2,
    const float* __restrict__ W3, __half* __restrict__ Wp3,
    const float* __restrict__ W4, __half* __restrict__ Wp4,
    const float* __restrict__ Wr, __half* __restrict__ Wrp,
    const float* __restrict__ Wf1, __half* __restrict__ Wf1p,
    const float* __restrict__ x, __half* __restrict__ Ch,
    const float* __restrict__ a_src, const float* __restrict__ a_dst,
    float* __restrict__ as_out, float* __restrict__ ad_out) {
  int b = blockIdx.x;
  if (b >= NT) {
    int b2 = b - NT;
    if (b2 < SCAT2_B) {
      int e0 = (b2 * 256 + threadIdx.x) * 4;
      if (e0 < NE) {                       // NE % 4 == 0: quad never straddles
        int4 s4 = *(const int4*)(edge_src + e0);
        int4 d4 = *(const int4*)(edge_dst + e0);
        int p0 = atomicAdd(&count[d4.x], 1);
        int p1 = atomicAdd(&count[d4.y], 1);
        int p2 = atomicAdd(&count[d4.z], 1);
        int p3 = atomicAdd(&count[d4.w], 1);
        if (p0 < CAP - 1) csr_src[d4.x * CAP + p0] = s4.x;
        if (p1 < CAP - 1) csr_src[d4.y * CAP + p1] = s4.y;
        if (p2 < CAP - 1) csr_src[d4.z * CAP + p2] = s4.z;
        if (p3 < CAP - 1) csr_src[d4.w * CAP + p3] = s4.w;
      }
      return;
    }
    int tid = (b2 - SCAT2_B) * 256 + threadIdx.x;
    if (tid < 256)            pack_w_one(W2, Wp2, 64,  tid,        256);
    else if (tid < 1280)      pack_w_one(W3, Wp3, 128, tid - 256,  1024);
    else if (tid < 5376)      pack_w_one(W4, Wp4, 256, tid - 1280, 4096);
    else if (tid < 6400)      pack_w_one(Wr, Wrp, 32,  tid - 5376, 1024);
    else if (tid < 6656)      pack_w_one(Wf1, Wf1p, 64, tid - 6400, 256);
    return;
  }

  // ---- gemm1: x[NN,128] @ W1[128,32] -> Ch fp16, + alpha epilogue ----
  constexpr int M = 32, K = 128, CT = 2, KC = 4;
  __shared__ _Float16 Ah[64 * 40];
  __shared__ _Float16 Bs[KC * CT * 64 * 8];   // 4096 halves = 8 KB
  int t = threadIdx.x;
  int w = t >> 6, l = t & 63;
  int m = l & 15, q = l >> 4;
  int row0 = b * 64;

  // pack W1 into LDS B-fragment layout (each thread: 2 frag-lane units)
  #pragma unroll
  for (int u0 = 0; u0 < 2; u0++) {
    int u = t + u0 * 256;            // 512 units total
    int ul = u & 63;
    int uc = (u >> 6) & 1;
    int ukc = u >> 7;
    int un = ul & 15, uq = ul >> 4;
    const float* src = W1 + (size_t)(ukc * 32 + uq * 8) * M + uc * 16 + un;
    _Float16* dst = &Bs[u * 8];
    #pragma unroll
    for (int j = 0; j < 8; j++) dst[j] = (_Float16)src[j * M];
  }

  f32x4_t acc[CT];
  #pragma unroll
  for (int c = 0; c < CT; c++) acc[c] = (f32x4_t){0.f, 0.f, 0.f, 0.f};

  for (int kc = 0; kc < KC; kc++) {
    __syncthreads();
    #pragma unroll
    for (int i = 0; i < 2; i++) {
      int idx = t + 256 * i;
      int row = idx >> 3, c4 = idx & 7;
      int gr = row0 + row; if (gr >= NN) gr = NN - 1;
      float4 v = *(const float4*)(x + (size_t)gr * K + kc * 32 + c4 * 4);
      _Float16 h4[4] = {(_Float16)v.x, (_Float16)v.y, (_Float16)v.z, (_Float16)v.w};
      *(uint2*)(&Ah[row * 40 + c4 * 4]) = *(const uint2*)h4;
    }
    __syncthreads();
    half8_t a = *(const half8_t*)(&Ah[(w * 16 + m) * 40 + q * 8]);
    #pragma unroll
    for (int c = 0; c < CT; c++) {
      half8_t bf = *(const half8_t*)(&Bs[((kc * CT + c) * 64 + l) * 8]);
      acc[c] = __builtin_amdgcn_mfma_f32_16x16x32_f16(a, bf, acc[c], 0, 0, 0);
    }
  }

  #pragma unroll
  for (int r = 0; r < 4; r++) {
    int row = row0 + w * 16 + q * 4 + r;
    if (row < NN) {
      #pragma unroll
      for (int c = 0; c < CT; c++)
        Ch[(size_t)row * M + c * 16 + m] = __float2half_rn(acc[c][r]);
    }
  }
  alpha_epilogue<M, 8, CT>(acc, a_src, a_dst, row0 + w * 16 + q * 4, m, as_out, ad_out);
}

// ---------------- MFMA GEMM (fp16 A) + fused alpha ----------

template<int M, int K, int C>
__global__ __launch_bounds__(256) void gemm_mfma_f16_kernel(const __half* __restrict__ A,
    const __half* __restrict__ Wp, __half* __restrict__ Ch,
    const float* __restrict__ a_src, const float* __restrict__ a_dst,
    float* __restrict__ as_out, float* __restrict__ ad_out) {
  constexpr int CT = M / 16;
  constexpr int KC = K / 32;
  __shared__ _Float16 Ah[64 * 40];
  int t = threadIdx.x;
  int w = t >> 6, l = t & 63;
  int m = l & 15, q = l >> 4;
  int row0 = blockIdx.x * 64;

  f32x4_t acc[CT];
  #pragma unroll
  for (int c = 0; c < CT; c++) acc[c] = (f32x4_t){0.f, 0.f, 0.f, 0.f};

  const half8_t* Bfrag = (const half8_t*)Wp;

  for (int kc = 0; kc < KC; kc++) {
    __syncthreads();
    {
      int row = t >> 2, c8 = t & 3;
      int gr = row0 + row; if (gr >= NN) gr = NN - 1;
      uint4 v = *(const uint4*)(A + (size_t)gr * K + kc * 32 + c8 * 8);
      *(uint4*)(&Ah[row * 40 + c8 * 8]) = v;
    }
    __syncthreads();
    half8_t a = *(const half8_t*)(&Ah[(w * 16 + m) * 40 + q * 8]);
    #pragma unroll
    for (int c = 0; c < CT; c++) {
      half8_t b = Bfrag[(kc * CT + c) * 64 + l];
      acc[c] = __builtin_amdgcn_mfma_f32_16x16x32_f16(a, b, acc[c], 0, 0, 0);
    }
  }

  #pragma unroll
  for (int r = 0; r < 4; r++) {
    int row = row0 + w * 16 + q * 4 + r;
    if (row < NN) {
      #pragma unroll
      for (int c = 0; c < CT; c++)
        Ch[(size_t)row * M + c * 16 + m] = __float2half_rn(acc[c][r]);
    }
  }
  alpha_epilogue<M, C, CT>(acc, a_src, a_dst, row0 + w * 16 + q * 4, m, as_out, ad_out);
}

// ---------------- aggregation: one wave per dst node (bucket CSR) ----------
// Slot 0 of every bucket is the implicit self-loop (src = dst); csr_src holds
// the real edges shifted by one. Inner loop consumes EXACTLY `steps` k-steps
// (full P-blocks + tail) instead of rounding up — padding cost was ~1.8-2.7x.

template<int HC, int C>
__global__ __launch_bounds__(256) void agg_kernel(const __half* __restrict__ h,
    const float* __restrict__ as_v, const float* __restrict__ ad_v,
    const int* __restrict__ count, const int* __restrict__ csr_src,
    const float* __restrict__ bias, __half* __restrict__ out) {
  constexpr int V = HC / 8;
  constexpr int G = 64 / V;
  constexpr int P = 4;
  __shared__ float4 see4[4][CAP];
  __shared__ int    ssrc[4][CAP];
  int wid = threadIdx.x >> 6, lane = threadIdx.x & 63;
  int dst = blockIdx.x * 4 + wid;          // grid is exactly NN/4
  int base = dst * CAP;
  int degE = count[dst]; if (degE > CAP - 1) degE = CAP - 1;
  int deg = degE + 1;                      // + implicit self-loop at slot 0
  float4 ad = *(const float4*)(ad_v + dst * 4);

  float d0 = 0.f, d1 = 0.f, d2 = 0.f, d3 = 0.f;
  #pragma unroll
  for (int it = 0; it < 2; it++) {
    int j = lane + it * 64;
    if (j < deg) {
      int s = (j == 0) ? dst : csr_src[base + j - 1];
      float4 as = *(const float4*)(as_v + s * 4);
      float4 x = make_float4(__expf(lrelu02(as.x + ad.x)), __expf(lrelu02(as.y + ad.y)),
                             __expf(lrelu02(as.z + ad.z)), __expf(lrelu02(as.w + ad.w)));
      ssrc[wid][j] = s; see4[wid][j] = x;
      d0 += x.x; d1 += x.y; d2 += x.z; d3 += x.w;
    }
  }
  #pragma unroll
  for (int off = 32; off > 0; off >>= 1) {
    d0 += __shfl_xor(d0, off); d1 += __shfl_xor(d1, off);
    d2 += __shfl_xor(d2, off); d3 += __shfl_xor(d3, off);
  }
  float4 inv = make_float4(1.f / d0, 1.f / d1, 1.f / d2, 1.f / d3);

  // fold 1/denom into the stored exp values (per-wave LDS, wave-coherent)
  #pragma unroll
  for (int it = 0; it < 2; it++) {
    int j = lane + it * 64;
    if (j < deg) {
      float4 xx = see4[wid][j];
      xx.x *= inv.x; xx.y *= inv.y; xx.z *= inv.z; xx.w *= inv.w;
      see4[wid][j] = xx;
    }
  }

  int g = lane / V, v = lane % V;
  int hd = (v * 8) / C;
  int steps = (deg + G - 1) / G;           // >= 1
  const float4* hrows = (const float4*)h;

  float  px[P];
  float4 hv[P];
  #pragma unroll
  for (int k = 0; k < P; k++) {
    int jj = k * G + g;
    bool ok = jj < deg;
    int jc = ok ? jj : 0;
    int s = ssrc[wid][jc];
    float x = ((const float*)&see4[wid][jc])[hd];
    px[k] = ok ? x : 0.f;
    hv[k] = hrows[(size_t)s * V + v];
  }

  float acc[8];
  #pragma unroll
  for (int i = 0; i < 8; i++) acc[i] = 0.f;

  int nBf = steps >> 2;                    // full P-blocks (pipelined)
  for (int b = 1; b <= nBf; b++) {
    #pragma unroll
    for (int k = 0; k < P; k++) {
      const _Float16* hh = (const _Float16*)&hv[k];
      float p = px[k];
      #pragma unroll
      for (int i = 0; i < 8; i++) acc[i] += p * (float)hh[i];   // v_fma_mix_f32
      int jj = (b * P + k) * G + g;
      bool ok = jj < deg;
      int jc = ok ? jj : 0;
      int s = ssrc[wid][jc];
      float x = ((const float*)&see4[wid][jc])[hd];
      px[k] = ok ? x : 0.f;
      hv[k] = hrows[(size_t)s * V + v];
    }
  }
  int rem = steps & 3;                     // 0..3 remaining k-steps
  #pragma unroll
  for (int k = 0; k < P - 1; k++) {
    if (k < rem) {
      const _Float16* hh = (const _Float16*)&hv[k];
      float p = px[k];
      #pragma unroll
      for (int i = 0; i < 8; i++) acc[i] += p * (float)hh[i];
    }
  }

  #pragma unroll
  for (int off = V; off < 64; off <<= 1)
    #pragma unroll
    for (int i = 0; i < 8; i++) acc[i] += __shfl_xor(acc[i], off);

  if (lane < V) {
    const float4* b4 = (const float4*)bias;
    float4 ba = b4[2 * v], bb = b4[2 * v + 1];
    _Float16 o[8];
    o[0] = (_Float16)eluf(acc[0] + ba.x); o[1] = (_Float16)eluf(acc[1] + ba.y);
    o[2] = (_Float16)eluf(acc[2] + ba.z); o[3] = (_Float16)eluf(acc[3] + ba.w);
    o[4] = (_Float16)eluf(acc[4] + bb.x); o[5] = (_Float16)eluf(acc[5] + bb.y);
    o[6] = (_Float16)eluf(acc[6] + bb.z); o[7] = (_Float16)eluf(acc[7] + bb.w);
    *(uint4*)(out + (size_t)dst * HC + v * 8) = *(const uint4*)o;
  }
}

// ---------------- MFMA MLP head: 256 -> 32 -> 64 -> 1 ----------------

__global__ __launch_bounds__(256) void mlp_mfma_kernel(const __half* __restrict__ h4,
    const __half* __restrict__ Wrp, const float* __restrict__ br,
    const __half* __restrict__ Wf1p, const float* __restrict__ bf1,
    const float* __restrict__ Wf2, const float* __restrict__ bf2,
    float* __restrict__ out) {
  __shared__ _Float16 rS[64 * 40];
  int t = threadIdx.x;
  int w = t >> 6, l = t & 63;
  int m = l & 15, q = l >> 4;
  int row0 = blockIdx.x * 64;
  const half8_t* Bwr  = (const half8_t*)Wrp;
  const half8_t* Bwf1 = (const half8_t*)Wf1p;

  int arow = row0 + w * 16 + m; if (arow >= NN) arow = NN - 1;
  const half8_t* Arow = (const half8_t*)(h4 + (size_t)arow * 256);
  half8_t afr[8];
  #pragma unroll
  for (int kc = 0; kc < 8; kc++) afr[kc] = Arow[kc * 4 + q];
  f32x4_t acc1[2];
  acc1[0] = (f32x4_t){0.f, 0.f, 0.f, 0.f};
  acc1[1] = (f32x4_t){0.f, 0.f, 0.f, 0.f};
  #pragma unroll
  for (int kc = 0; kc < 8; kc++) {
    acc1[0] = __builtin_amdgcn_mfma_f32_16x16x32_f16(afr[kc], Bwr[(kc * 2 + 0) * 64 + l], acc1[0], 0, 0, 0);
    acc1[1] = __builtin_amdgcn_mfma_f32_16x16x32_f16(afr[kc], Bwr[(kc * 2 + 1) * 64 + l], acc1[1], 0, 0, 0);
  }
  #pragma unroll
  for (int c = 0; c < 2; c++)
    #pragma unroll
    for (int r = 0; r < 4; r++) {
      float vv = eluf(acc1[c][r] + br[c * 16 + m]);
      rS[(w * 16 + q * 4 + r) * 40 + c * 16 + m] = (_Float16)vv;
    }
  __syncthreads();

  half8_t a2 = *(const half8_t*)(&rS[(w * 16 + m) * 40 + q * 8]);
  f32x4_t acc2[4];
  #pragma unroll
  for (int c = 0; c < 4; c++) acc2[c] = (f32x4_t){0.f, 0.f, 0.f, 0.f};
  #pragma unroll
  for (int c = 0; c < 4; c++)
    acc2[c] = __builtin_amdgcn_mfma_f32_16x16x32_f16(a2, Bwf1[c * 64 + l], acc2[c], 0, 0, 0);

  float wv[4] = {Wf2[m], Wf2[16 + m], Wf2[32 + m], Wf2[48 + m]};
  float rsum[4];
  #pragma unroll
  for (int r = 0; r < 4; r++) {
    float sr = 0.f;
    #pragma unroll
    for (int c = 0; c < 4; c++)
      sr += eluf(acc2[c][r] + bf1[c * 16 + m]) * wv[c];
    #pragma unroll
    for (int off = 1; off < 16; off <<= 1) sr += __shfl_xor(sr, off);
    rsum[r] = sr;
  }
  if (m == 0) {
    float b = bf2[0];
    #pragma unroll
    for (int r = 0; r < 4; r++) {
      int row = row0 + w * 16 + q * 4 + r;
      if (row < NN) out[row] = rsum[r] + b;
    }
  }
}

// ---------------- launcher ----------------

extern "C" void kernel_launch(void* const* d_in, const int* in_sizes, int n_in,
                              void* d_out, int out_size, void* d_ws, size_t ws_size,
                              hipStream_t stream) {
  const float* x   = (const float*)d_in[0];
  const int*   ei  = (const int*)d_in[1];
  const float* W1  = (const float*)d_in[3];
  const float* as1 = (const float*)d_in[4];
  const float* ad1 = (const float*)d_in[5];
  const float* b1  = (const float*)d_in[6];
  const float* W2  = (const float*)d_in[7];
  const float* as2 = (const float*)d_in[8];
  const float* ad2 = (const float*)d_in[9];
  const float* b2  = (const float*)d_in[10];
  const float* W3  = (const float*)d_in[11];
  const float* as3 = (const float*)d_in[12];
  const float* ad3 = (const float*)d_in[13];
  const float* b3  = (const float*)d_in[14];
  const float* W4  = (const float*)d_in[15];
  const float* as4 = (const float*)d_in[16];
  const float* ad4 = (const float*)d_in[17];
  const float* b4  = (const float*)d_in[18];
  const float* Wr  = (const float*)d_in[19];
  const float* br  = (const float*)d_in[20];
  const float* Wf1 = (const float*)d_in[21];
  const float* bf1 = (const float*)d_in[22];
  const float* Wf2 = (const float*)d_in[23];
  const float* bf2 = (const float*)d_in[24];
  float* out = (float*)d_out;

  char* p = (char*)d_ws;
  auto alloc = [&](size_t bytes) {
    char* q = p;
    p += (bytes + 255) & ~(size_t)255;
    return q;
  };
  int* count   = (int*)alloc((size_t)NN * 4);
  int* csr_src = (int*)alloc((size_t)NN * CAP * 4);
  __half* Hh = (__half*)alloc((size_t)NN * 256 * 2);  // fp16 h (gather payload)
  __half* B2 = (__half*)alloc((size_t)NN * 128 * 2);  // agg out (layers 1/3)
  __half* B3 = (__half*)alloc((size_t)NN * 256 * 2);  // agg out (layers 2/4)
  float* as_buf = (float*)alloc((size_t)NN * 4 * 4);
  float* ad_buf = (float*)alloc((size_t)NN * 4 * 4);
  __half* Wp2 = (__half*)alloc((size_t)32 * 64 * 2);
  __half* Wp3 = (__half*)alloc((size_t)64 * 128 * 2);
  __half* Wp4 = (__half*)alloc((size_t)128 * 256 * 2);
  __half* Wrp = (__half*)alloc((size_t)256 * 32 * 2);
  __half* Wf1p = (__half*)alloc((size_t)32 * 64 * 2);

  const int* edge_src = ei;
  const int* edge_dst = ei + NE;

  hipMemsetAsync(count, 0, (size_t)NN * 4, stream);
  // gemm1 (+alpha1) | scatter | pack in one kernel — independent block ranges
  front_kernel<<<NT + SCAT2_B + PACK_B, 256, 0, stream>>>(
      edge_src, edge_dst, count, csr_src,
      W1, W2, Wp2, W3, Wp3, W4, Wp4, Wr, Wrp, Wf1, Wf1p,
      x, Hh, as1, ad1, as_buf, ad_buf);

  int gb  = NT;
  int ggb = NN / 4;   // NN % 4 == 0

  agg_kernel<32, 8><<<ggb, 256, 0, stream>>>(Hh, as_buf, ad_buf, count, csr_src, b1, B2);

  gemm_mfma_f16_kernel<64, 32, 16><<<gb, 256, 0, stream>>>(B2, Wp2, Hh, as2, ad2, as_buf, ad_buf);
  agg_kernel<64, 16><<<ggb, 256, 0, stream>>>(Hh, as_buf, ad_buf, count, csr_src, b2, B3);

  gemm_mfma_f16_kernel<128, 64, 32><<<gb, 256, 0, stream>>>(B3, Wp3, Hh, as3, ad3, as_buf, ad_buf);
  agg_kernel<128, 32><<<ggb, 256, 0, stream>>>(Hh, as_buf, ad_buf, count, csr_src, b3, B2);

  gemm_mfma_f16_kernel<256, 128, 64><<<gb, 256, 0, stream>>>(B2, Wp4, Hh, as4, ad4, as_buf, ad_buf);
  agg_kernel<256, 64><<<ggb, 256, 0, stream>>>(Hh, as_buf, ad_buf, count, csr_src, b4, B3);

  mlp_mfma_kernel<<<gb, 256, 0, stream>>>(B3, Wrp, br, Wf1p, bf1, Wf2, bf2, out);
}

// Round 3
// 389.461 us; speedup vs baseline: 1.2493x; 1.2493x over previous
//
#include <hip/hip_runtime.h>
#include <hip/hip_fp16.h>
#include <math.h>

constexpr int NN = 50000;
constexpr int NE = 800000;
constexpr int NEP = NE + NN;             // edges + self-loops
constexpr int CAP = 96;                  // bucket capacity (slot 0 = implicit self-loop)
constexpr int SCAT2_B = (NE / 4 + 255) / 256;  // 782 blocks, 4 edges/thread
constexpr int PACK_B = 26;                     // 6656 pack threads (W2..Wf1)
constexpr int NT = (NN + 63) / 64;             // 782 gemm tiles

typedef _Float16 half8_t __attribute__((ext_vector_type(8)));
typedef float    f32x4_t __attribute__((ext_vector_type(4)));

__device__ __forceinline__ float lrelu02(float x) { return x > 0.f ? x : 0.2f * x; }
__device__ __forceinline__ float eluf(float x)    { return x > 0.f ? x : (__expf(x) - 1.f); }
__device__ __forceinline__ float pick4(float4 q, int hd) {
  return (hd == 0) ? q.x : (hd == 1) ? q.y : (hd == 2) ? q.z : q.w;
}

// ---------------- W pre-pack into MFMA B-fragment order ----------------

__device__ __forceinline__ void pack_w_one(const float* __restrict__ W,
                                           __half* __restrict__ Wp,
                                           int M, int tid, int total) {
  if (tid >= total) return;
  int CT = M >> 4;
  int l = tid & 63;
  int c = (tid >> 6) % CT;
  int kc = (tid >> 6) / CT;
  int n = l & 15, q = l >> 4;
  __half* dst = Wp + (size_t)tid * 8;
  const float* src = W + (size_t)(kc * 32 + q * 8) * M + c * 16 + n;
  #pragma unroll
  for (int j = 0; j < 8; j++) dst[j] = __float2half_rn(src[j * M]);
}

// ---------------- fused alpha epilogue ----------

template<int M, int C, int CT>
__device__ __forceinline__ void alpha_epilogue(const f32x4_t* acc,
    const float* __restrict__ a_src, const float* __restrict__ a_dst,
    int row_base, int m, float* __restrict__ as_out, float* __restrict__ ad_out) {
  float aS[CT], aD[CT];
  #pragma unroll
  for (int c = 0; c < CT; c++) { aS[c] = a_src[c * 16 + m]; aD[c] = a_dst[c * 16 + m]; }

  if constexpr (C == 8) {
    #pragma unroll
    for (int r = 0; r < 4; r++) {
      float p0 = acc[0][r] * aS[0], p1 = acc[1][r] * aS[1];
      float q0 = acc[0][r] * aD[0], q1 = acc[1][r] * aD[1];
      #pragma unroll
      for (int off = 1; off < 8; off <<= 1) {
        p0 += __shfl_xor(p0, off); p1 += __shfl_xor(p1, off);
        q0 += __shfl_xor(q0, off); q1 += __shfl_xor(q1, off);
      }
      int row = row_base + r;
      if ((m & 7) == 0 && row < NN) {
        int hb = m >> 3;
        as_out[row * 4 + hb]     = p0;
        as_out[row * 4 + 2 + hb] = p1;
        ad_out[row * 4 + hb]     = q0;
        ad_out[row * 4 + 2 + hb] = q1;
      }
    }
  } else {
    constexpr int FPH = C / 16;
    #pragma unroll
    for (int r = 0; r < 4; r++) {
      float bs[4] = {0.f, 0.f, 0.f, 0.f}, bd[4] = {0.f, 0.f, 0.f, 0.f};
      #pragma unroll
      for (int c = 0; c < CT; c++) {
        int hd = c / FPH;
        bs[hd] += acc[c][r] * aS[c];
        bd[hd] += acc[c][r] * aD[c];
      }
      #pragma unroll
      for (int off = 1; off < 16; off <<= 1)
        #pragma unroll
        for (int h = 0; h < 4; h++) {
          bs[h] += __shfl_xor(bs[h], off);
          bd[h] += __shfl_xor(bd[h], off);
        }
      int row = row_base + r;
      if (m < 4 && row < NN) {
        float vs = (m == 0) ? bs[0] : (m == 1) ? bs[1] : (m == 2) ? bs[2] : bs[3];
        float vd = (m == 0) ? bd[0] : (m == 1) ? bd[1] : (m == 2) ? bd[2] : bd[3];
        as_out[row * 4 + m] = vs;
        ad_out[row * 4 + m] = vd;
      }
    }
  }
}

// ---------------- merged front kernel: gemm1 | scatter | pack(W2..Wf1) ------
// gemm1 blocks come FIRST so MFMA work starts immediately; the latency-bound
// scatter blocks fill in around it. Self-loops are implicit (slot 0 == dst),
// so the scatter only covers the NE real edges, 4 per thread for ILP.

__global__ __launch_bounds__(256) void front_kernel(
    const int* __restrict__ edge_src, const int* __restrict__ edge_dst,
    int* __restrict__ count, int* __restrict__ csr_src,
    const float* __restrict__ W1,
    const float* __restrict__ W2, __half* __restrict__ Wp2,
    const float* __restrict__ W3, __half* __restrict__ Wp3,
    const float* __restrict__ W4, __half* __restrict__ Wp4,
    const float* __restrict__ Wr, __half* __restrict__ Wrp,
    const float* __restrict__ Wf1, __half* __restrict__ Wf1p,
    const float* __restrict__ x, __half* __restrict__ Ch,
    const float* __restrict__ a_src, const float* __restrict__ a_dst,
    float* __restrict__ as_out, float* __restrict__ ad_out) {
  int b = blockIdx.x;
  if (b >= NT) {
    int b2 = b - NT;
    if (b2 < SCAT2_B) {
      int e0 = (b2 * 256 + threadIdx.x) * 4;
      if (e0 < NE) {                       // NE % 4 == 0: quad never straddles
        int4 s4 = *(const int4*)(edge_src + e0);
        int4 d4 = *(const int4*)(edge_dst + e0);
        int p0 = atomicAdd(&count[d4.x], 1);
        int p1 = atomicAdd(&count[d4.y], 1);
        int p2 = atomicAdd(&count[d4.z], 1);
        int p3 = atomicAdd(&count[d4.w], 1);
        if (p0 < CAP - 1) csr_src[d4.x * CAP + p0] = s4.x;
        if (p1 < CAP - 1) csr_src[d4.y * CAP + p1] = s4.y;
        if (p2 < CAP - 1) csr_src[d4.z * CAP + p2] = s4.z;
        if (p3 < CAP - 1) csr_src[d4.w * CAP + p3] = s4.w;
      }
      return;
    }
    int tid = (b2 - SCAT2_B) * 256 + threadIdx.x;
    if (tid < 256)            pack_w_one(W2, Wp2, 64,  tid,        256);
    else if (tid < 1280)      pack_w_one(W3, Wp3, 128, tid - 256,  1024);
    else if (tid < 5376)      pack_w_one(W4, Wp4, 256, tid - 1280, 4096);
    else if (tid < 6400)      pack_w_one(Wr, Wrp, 32,  tid - 5376, 1024);
    else if (tid < 6656)      pack_w_one(Wf1, Wf1p, 64, tid - 6400, 256);
    return;
  }

  // ---- gemm1: x[NN,128] @ W1[128,32] -> Ch fp16, + alpha epilogue ----
  constexpr int M = 32, K = 128, CT = 2, KC = 4;
  __shared__ _Float16 Ah[64 * 40];
  __shared__ _Float16 Bs[KC * CT * 64 * 8];   // 4096 halves = 8 KB
  int t = threadIdx.x;
  int w = t >> 6, l = t & 63;
  int m = l & 15, q = l >> 4;
  int row0 = b * 64;

  // pack W1 into LDS B-fragment layout (each thread: 2 frag-lane units)
  #pragma unroll
  for (int u0 = 0; u0 < 2; u0++) {
    int u = t + u0 * 256;            // 512 units total
    int ul = u & 63;
    int uc = (u >> 6) & 1;
    int ukc = u >> 7;
    int un = ul & 15, uq = ul >> 4;
    const float* src = W1 + (size_t)(ukc * 32 + uq * 8) * M + uc * 16 + un;
    _Float16* dst = &Bs[u * 8];
    #pragma unroll
    for (int j = 0; j < 8; j++) dst[j] = (_Float16)src[j * M];
  }

  f32x4_t acc[CT];
  #pragma unroll
  for (int c = 0; c < CT; c++) acc[c] = (f32x4_t){0.f, 0.f, 0.f, 0.f};

  for (int kc = 0; kc < KC; kc++) {
    __syncthreads();
    #pragma unroll
    for (int i = 0; i < 2; i++) {
      int idx = t + 256 * i;
      int row = idx >> 3, c4 = idx & 7;
      int gr = row0 + row; if (gr >= NN) gr = NN - 1;
      float4 v = *(const float4*)(x + (size_t)gr * K + kc * 32 + c4 * 4);
      _Float16 h4[4] = {(_Float16)v.x, (_Float16)v.y, (_Float16)v.z, (_Float16)v.w};
      *(uint2*)(&Ah[row * 40 + c4 * 4]) = *(const uint2*)h4;
    }
    __syncthreads();
    half8_t a = *(const half8_t*)(&Ah[(w * 16 + m) * 40 + q * 8]);
    #pragma unroll
    for (int c = 0; c < CT; c++) {
      half8_t bf = *(const half8_t*)(&Bs[((kc * CT + c) * 64 + l) * 8]);
      acc[c] = __builtin_amdgcn_mfma_f32_16x16x32_f16(a, bf, acc[c], 0, 0, 0);
    }
  }

  #pragma unroll
  for (int r = 0; r < 4; r++) {
    int row = row0 + w * 16 + q * 4 + r;
    if (row < NN) {
      #pragma unroll
      for (int c = 0; c < CT; c++)
        Ch[(size_t)row * M + c * 16 + m] = __float2half_rn(acc[c][r]);
    }
  }
  alpha_epilogue<M, 8, CT>(acc, a_src, a_dst, row0 + w * 16 + q * 4, m, as_out, ad_out);
}

// ---------------- MFMA GEMM (fp16 A) + fused alpha ----------

template<int M, int K, int C>
__global__ __launch_bounds__(256) void gemm_mfma_f16_kernel(const __half* __restrict__ A,
    const __half* __restrict__ Wp, __half* __restrict__ Ch,
    const float* __restrict__ a_src, const float* __restrict__ a_dst,
    float* __restrict__ as_out, float* __restrict__ ad_out) {
  constexpr int CT = M / 16;
  constexpr int KC = K / 32;
  __shared__ _Float16 Ah[64 * 40];
  int t = threadIdx.x;
  int w = t >> 6, l = t & 63;
  int m = l & 15, q = l >> 4;
  int row0 = blockIdx.x * 64;

  f32x4_t acc[CT];
  #pragma unroll
  for (int c = 0; c < CT; c++) acc[c] = (f32x4_t){0.f, 0.f, 0.f, 0.f};

  const half8_t* Bfrag = (const half8_t*)Wp;

  for (int kc = 0; kc < KC; kc++) {
    __syncthreads();
    {
      int row = t >> 2, c8 = t & 3;
      int gr = row0 + row; if (gr >= NN) gr = NN - 1;
      uint4 v = *(const uint4*)(A + (size_t)gr * K + kc * 32 + c8 * 8);
      *(uint4*)(&Ah[row * 40 + c8 * 8]) = v;
    }
    __syncthreads();
    half8_t a = *(const half8_t*)(&Ah[(w * 16 + m) * 40 + q * 8]);
    #pragma unroll
    for (int c = 0; c < CT; c++) {
      half8_t b = Bfrag[(kc * CT + c) * 64 + l];
      acc[c] = __builtin_amdgcn_mfma_f32_16x16x32_f16(a, b, acc[c], 0, 0, 0);
    }
  }

  #pragma unroll
  for (int r = 0; r < 4; r++) {
    int row = row0 + w * 16 + q * 4 + r;
    if (row < NN) {
      #pragma unroll
      for (int c = 0; c < CT; c++)
        Ch[(size_t)row * M + c * 16 + m] = __float2half_rn(acc[c][r]);
    }
  }
  alpha_epilogue<M, C, CT>(acc, a_src, a_dst, row0 + w * 16 + q * 4, m, as_out, ad_out);
}

// ---------------- aggregation: one wave per dst node (bucket CSR) ----------
// Slot 0 of every bucket is the implicit self-loop (src = dst); csr_src holds
// the real edges shifted by one. Inner loop is the round-0 proven pipelined
// structure (padded P-blocks, __half22float2 MAC, invh in register) — the
// exact-steps rewrite halved memory-issue rate and was reverted.

template<int HC, int C>
__global__ __launch_bounds__(256) void agg_kernel(const __half* __restrict__ h,
    const float* __restrict__ as_v, const float* __restrict__ ad_v,
    const int* __restrict__ count, const int* __restrict__ csr_src,
    const float* __restrict__ bias, __half* __restrict__ out) {
  constexpr int V = HC / 8;
  constexpr int G = 64 / V;
  constexpr int P = 4;
  __shared__ float4 see4[4][CAP];
  __shared__ int    ssrc[4][CAP];
  int wid = threadIdx.x >> 6, lane = threadIdx.x & 63;
  int dst = blockIdx.x * 4 + wid;          // grid is exactly NN/4
  int base = dst * CAP;
  int degE = count[dst]; if (degE > CAP - 1) degE = CAP - 1;
  int deg = degE + 1;                      // + implicit self-loop at slot 0
  float4 ad = *(const float4*)(ad_v + dst * 4);

  float d0 = 0.f, d1 = 0.f, d2 = 0.f, d3 = 0.f;
  #pragma unroll
  for (int it = 0; it < 2; it++) {
    int j = lane + it * 64;
    if (j < deg) {
      int s = (j == 0) ? dst : csr_src[base + j - 1];
      float4 as = *(const float4*)(as_v + s * 4);
      float4 x = make_float4(__expf(lrelu02(as.x + ad.x)), __expf(lrelu02(as.y + ad.y)),
                             __expf(lrelu02(as.z + ad.z)), __expf(lrelu02(as.w + ad.w)));
      ssrc[wid][j] = s; see4[wid][j] = x;
      d0 += x.x; d1 += x.y; d2 += x.z; d3 += x.w;
    }
  }
  #pragma unroll
  for (int off = 32; off > 0; off >>= 1) {
    d0 += __shfl_xor(d0, off); d1 += __shfl_xor(d1, off);
    d2 += __shfl_xor(d2, off); d3 += __shfl_xor(d3, off);
  }
  float4 inv = make_float4(1.f / d0, 1.f / d1, 1.f / d2, 1.f / d3);

  int g = lane / V, v = lane % V;
  int hd = (v * 8) / C;
  float invh = pick4(inv, hd);
  int steps = (deg + G - 1) / G;
  const float4* hrows = (const float4*)h;

  float  px[P];
  float4 hv[P];
  #pragma unroll
  for (int k = 0; k < P; k++) {
    int jj = k * G + g;
    bool ok = jj < deg;
    int jc = ok ? jj : 0;
    int s = ssrc[wid][jc];
    float x = ((const float*)&see4[wid][jc])[hd];
    px[k] = ok ? x * invh : 0.f;
    hv[k] = hrows[(size_t)s * V + v];
  }

  float acc[8];
  #pragma unroll
  for (int i = 0; i < 8; i++) acc[i] = 0.f;
  int nB = (steps + P - 1) / P;            // >= 1
  for (int b = 1; b <= nB; b++) {
    #pragma unroll
    for (int k = 0; k < P; k++) {
      const __half2* hp = (const __half2*)&hv[k];
      float2 f0 = __half22float2(hp[0]);
      float2 f1 = __half22float2(hp[1]);
      float2 f2 = __half22float2(hp[2]);
      float2 f3 = __half22float2(hp[3]);
      float p = px[k];
      acc[0] += p * f0.x; acc[1] += p * f0.y;
      acc[2] += p * f1.x; acc[3] += p * f1.y;
      acc[4] += p * f2.x; acc[5] += p * f2.y;
      acc[6] += p * f3.x; acc[7] += p * f3.y;
      int jj = (b * P + k) * G + g;
      bool ok = jj < deg;
      int jc = ok ? jj : 0;
      int s = ssrc[wid][jc];
      float x = ((const float*)&see4[wid][jc])[hd];
      px[k] = ok ? x * invh : 0.f;
      hv[k] = hrows[(size_t)s * V + v];
    }
  }

  #pragma unroll
  for (int off = V; off < 64; off <<= 1)
    #pragma unroll
    for (int i = 0; i < 8; i++) acc[i] += __shfl_xor(acc[i], off);

  if (lane < V) {
    const float4* b4 = (const float4*)bias;
    float4 ba = b4[2 * v], bb = b4[2 * v + 1];
    _Float16 o[8];
    o[0] = (_Float16)eluf(acc[0] + ba.x); o[1] = (_Float16)eluf(acc[1] + ba.y);
    o[2] = (_Float16)eluf(acc[2] + ba.z); o[3] = (_Float16)eluf(acc[3] + ba.w);
    o[4] = (_Float16)eluf(acc[4] + bb.x); o[5] = (_Float16)eluf(acc[5] + bb.y);
    o[6] = (_Float16)eluf(acc[6] + bb.z); o[7] = (_Float16)eluf(acc[7] + bb.w);
    *(uint4*)(out + (size_t)dst * HC + v * 8) = *(const uint4*)o;
  }
}

// ---------------- MFMA MLP head: 256 -> 32 -> 64 -> 1 ----------------

__global__ __launch_bounds__(256) void mlp_mfma_kernel(const __half* __restrict__ h4,
    const __half* __restrict__ Wrp, const float* __restrict__ br,
    const __half* __restrict__ Wf1p, const float* __restrict__ bf1,
    const float* __restrict__ Wf2, const float* __restrict__ bf2,
    float* __restrict__ out) {
  __shared__ _Float16 rS[64 * 40];
  int t = threadIdx.x;
  int w = t >> 6, l = t & 63;
  int m = l & 15, q = l >> 4;
  int row0 = blockIdx.x * 64;
  const half8_t* Bwr  = (const half8_t*)Wrp;
  const half8_t* Bwf1 = (const half8_t*)Wf1p;

  int arow = row0 + w * 16 + m; if (arow >= NN) arow = NN - 1;
  const half8_t* Arow = (const half8_t*)(h4 + (size_t)arow * 256);
  half8_t afr[8];
  #pragma unroll
  for (int kc = 0; kc < 8; kc++) afr[kc] = Arow[kc * 4 + q];
  f32x4_t acc1[2];
  acc1[0] = (f32x4_t){0.f, 0.f, 0.f, 0.f};
  acc1[1] = (f32x4_t){0.f, 0.f, 0.f, 0.f};
  #pragma unroll
  for (int kc = 0; kc < 8; kc++) {
    acc1[0] = __builtin_amdgcn_mfma_f32_16x16x32_f16(afr[kc], Bwr[(kc * 2 + 0) * 64 + l], acc1[0], 0, 0, 0);
    acc1[1] = __builtin_amdgcn_mfma_f32_16x16x32_f16(afr[kc], Bwr[(kc * 2 + 1) * 64 + l], acc1[1], 0, 0, 0);
  }
  #pragma unroll
  for (int c = 0; c < 2; c++)
    #pragma unroll
    for (int r = 0; r < 4; r++) {
      float vv = eluf(acc1[c][r] + br[c * 16 + m]);
      rS[(w * 16 + q * 4 + r) * 40 + c * 16 + m] = (_Float16)vv;
    }
  __syncthreads();

  half8_t a2 = *(const half8_t*)(&rS[(w * 16 + m) * 40 + q * 8]);
  f32x4_t acc2[4];
  #pragma unroll
  for (int c = 0; c < 4; c++) acc2[c] = (f32x4_t){0.f, 0.f, 0.f, 0.f};
  #pragma unroll
  for (int c = 0; c < 4; c++)
    acc2[c] = __builtin_amdgcn_mfma_f32_16x16x32_f16(a2, Bwf1[c * 64 + l], acc2[c], 0, 0, 0);

  float wv[4] = {Wf2[m], Wf2[16 + m], Wf2[32 + m], Wf2[48 + m]};
  float rsum[4];
  #pragma unroll
  for (int r = 0; r < 4; r++) {
    float sr = 0.f;
    #pragma unroll
    for (int c = 0; c < 4; c++)
      sr += eluf(acc2[c][r] + bf1[c * 16 + m]) * wv[c];
    #pragma unroll
    for (int off = 1; off < 16; off <<= 1) sr += __shfl_xor(sr, off);
    rsum[r] = sr;
  }
  if (m == 0) {
    float b = bf2[0];
    #pragma unroll
    for (int r = 0; r < 4; r++) {
      int row = row0 + w * 16 + q * 4 + r;
      if (row < NN) out[row] = rsum[r] + b;
    }
  }
}

// ---------------- launcher ----------------

extern "C" void kernel_launch(void* const* d_in, const int* in_sizes, int n_in,
                              void* d_out, int out_size, void* d_ws, size_t ws_size,
                              hipStream_t stream) {
  const float* x   = (const float*)d_in[0];
  const int*   ei  = (const int*)d_in[1];
  const float* W1  = (const float*)d_in[3];
  const float* as1 = (const float*)d_in[4];
  const float* ad1 = (const float*)d_in[5];
  const float* b1  = (const float*)d_in[6];
  const float* W2  = (const float*)d_in[7];
  const float* as2 = (const float*)d_in[8];
  const float* ad2 = (const float*)d_in[9];
  const float* b2  = (const float*)d_in[10];
  const float* W3  = (const float*)d_in[11];
  const float* as3 = (const float*)d_in[12];
  const float* ad3 = (const float*)d_in[13];
  const float* b3  = (const float*)d_in[14];
  const float* W4  = (const float*)d_in[15];
  const float* as4 = (const float*)d_in[16];
  const float* ad4 = (const float*)d_in[17];
  const float* b4  = (const float*)d_in[18];
  const float* Wr  = (const float*)d_in[19];
  const float* br  = (const float*)d_in[20];
  const float* Wf1 = (const float*)d_in[21];
  const float* bf1 = (const float*)d_in[22];
  const float* Wf2 = (const float*)d_in[23];
  const float* bf2 = (const float*)d_in[24];
  float* out = (float*)d_out;

  char* p = (char*)d_ws;
  auto alloc = [&](size_t bytes) {
    char* q = p;
    p += (bytes + 255) & ~(size_t)255;
    return q;
  };
  int* count   = (int*)alloc((size_t)NN * 4);
  int* csr_src = (int*)alloc((size_t)NN * CAP * 4);
  __half* Hh = (__half*)alloc((size_t)NN * 256 * 2);  // fp16 h (gather payload)
  __half* B2 = (__half*)alloc((size_t)NN * 128 * 2);  // agg out (layers 1/3)
  __half* B3 = (__half*)alloc((size_t)NN * 256 * 2);  // agg out (layers 2/4)
  float* as_buf = (float*)alloc((size_t)NN * 4 * 4);
  float* ad_buf = (float*)alloc((size_t)NN * 4 * 4);
  __half* Wp2 = (__half*)alloc((size_t)32 * 64 * 2);
  __half* Wp3 = (__half*)alloc((size_t)64 * 128 * 2);
  __half* Wp4 = (__half*)alloc((size_t)128 * 256 * 2);
  __half* Wrp = (__half*)alloc((size_t)256 * 32 * 2);
  __half* Wf1p = (__half*)alloc((size_t)32 * 64 * 2);

  const int* edge_src = ei;
  const int* edge_dst = ei + NE;

  hipMemsetAsync(count, 0, (size_t)NN * 4, stream);
  // gemm1 (+alpha1) | scatter | pack in one kernel — independent block ranges
  front_kernel<<<NT + SCAT2_B + PACK_B, 256, 0, stream>>>(
      edge_src, edge_dst, count, csr_src,
      W1, W2, Wp2, W3, Wp3, W4, Wp4, Wr, Wrp, Wf1, Wf1p,
      x, Hh, as1, ad1, as_buf, ad_buf);

  int gb  = NT;
  int ggb = NN / 4;   // NN % 4 == 0

  agg_kernel<32, 8><<<ggb, 256, 0, stream>>>(Hh, as_buf, ad_buf, count, csr_src, b1, B2);

  gemm_mfma_f16_kernel<64, 32, 16><<<gb, 256, 0, stream>>>(B2, Wp2, Hh, as2, ad2, as_buf, ad_buf);
  agg_kernel<64, 16><<<ggb, 256, 0, stream>>>(Hh, as_buf, ad_buf, count, csr_src, b2, B3);

  gemm_mfma_f16_kernel<128, 64, 32><<<gb, 256, 0, stream>>>(B3, Wp3, Hh, as3, ad3, as_buf, ad_buf);
  agg_kernel<128, 32><<<ggb, 256, 0, stream>>>(Hh, as_buf, ad_buf, count, csr_src, b3, B2);

  gemm_mfma_f16_kernel<256, 128, 64><<<gb, 256, 0, stream>>>(B2, Wp4, Hh, as4, ad4, as_buf, ad_buf);
  agg_kernel<256, 64><<<ggb, 256, 0, stream>>>(Hh, as_buf, ad_buf, count, csr_src, b4, B3);

  mlp_mfma_kernel<<<gb, 256, 0, stream>>>(B3, Wrp, br, Wf1p, bf1, Wf2, bf2, out);
}

// Round 4
// 385.041 us; speedup vs baseline: 1.2636x; 1.0115x over previous
//
#include <hip/hip_runtime.h>
#include <hip/hip_fp16.h>
#include <math.h>

constexpr int NN = 50000;
constexpr int NE = 800000;
constexpr int NEP = NE + NN;             // edges + self-loops
constexpr int CAP = 96;                  // bucket capacity (slot 0 = implicit self-loop)
constexpr int SCAT2_B = (NE / 4 + 255) / 256;  // 782 blocks, 4 edges/thread
constexpr int PACK_B = 26;                     // 6656 pack threads (W2..Wf1)
constexpr int NT = (NN + 63) / 64;             // 782 gemm tiles

typedef _Float16 half8_t __attribute__((ext_vector_type(8)));
typedef float    f32x4_t __attribute__((ext_vector_type(4)));

__device__ __forceinline__ float lrelu02(float x) { return x > 0.f ? x : 0.2f * x; }
__device__ __forceinline__ float eluf(float x)    { return x > 0.f ? x : (__expf(x) - 1.f); }
__device__ __forceinline__ float pick4(float4 q, int hd) {
  return (hd == 0) ? q.x : (hd == 1) ? q.y : (hd == 2) ? q.z : q.w;
}

// v_fma_mix_f32: acc(f32) += p(f32) * fp16-half of u — cvt+fma in ONE VALU op.
// sel=0 -> low 16 bits of u, sel=1 -> high 16 bits. Bit-identical to cvt+fma.
#define FMAMIX_LO(accv, pv, uv) \
  asm("v_fma_mix_f32 %0, %1, %2, %0 op_sel:[0,0,0] op_sel_hi:[0,1,0]" \
      : "+v"(accv) : "v"(pv), "v"(uv))
#define FMAMIX_HI(accv, pv, uv) \
  asm("v_fma_mix_f32 %0, %1, %2, %0 op_sel:[0,1,0] op_sel_hi:[0,1,0]" \
      : "+v"(accv) : "v"(pv), "v"(uv))

// ---------------- W pre-pack into MFMA B-fragment order ----------------

__device__ __forceinline__ void pack_w_one(const float* __restrict__ W,
                                           __half* __restrict__ Wp,
                                           int M, int tid, int total) {
  if (tid >= total) return;
  int CT = M >> 4;
  int l = tid & 63;
  int c = (tid >> 6) % CT;
  int kc = (tid >> 6) / CT;
  int n = l & 15, q = l >> 4;
  __half* dst = Wp + (size_t)tid * 8;
  const float* src = W + (size_t)(kc * 32 + q * 8) * M + c * 16 + n;
  #pragma unroll
  for (int j = 0; j < 8; j++) dst[j] = __float2half_rn(src[j * M]);
}

// ---------------- fused alpha epilogue ----------

template<int M, int C, int CT>
__device__ __forceinline__ void alpha_epilogue(const f32x4_t* acc,
    const float* __restrict__ a_src, const float* __restrict__ a_dst,
    int row_base, int m, float* __restrict__ as_out, float* __restrict__ ad_out) {
  float aS[CT], aD[CT];
  #pragma unroll
  for (int c = 0; c < CT; c++) { aS[c] = a_src[c * 16 + m]; aD[c] = a_dst[c * 16 + m]; }

  if constexpr (C == 8) {
    #pragma unroll
    for (int r = 0; r < 4; r++) {
      float p0 = acc[0][r] * aS[0], p1 = acc[1][r] * aS[1];
      float q0 = acc[0][r] * aD[0], q1 = acc[1][r] * aD[1];
      #pragma unroll
      for (int off = 1; off < 8; off <<= 1) {
        p0 += __shfl_xor(p0, off); p1 += __shfl_xor(p1, off);
        q0 += __shfl_xor(q0, off); q1 += __shfl_xor(q1, off);
      }
      int row = row_base + r;
      if ((m & 7) == 0 && row < NN) {
        int hb = m >> 3;
        as_out[row * 4 + hb]     = p0;
        as_out[row * 4 + 2 + hb] = p1;
        ad_out[row * 4 + hb]     = q0;
        ad_out[row * 4 + 2 + hb] = q1;
      }
    }
  } else {
    constexpr int FPH = C / 16;
    #pragma unroll
    for (int r = 0; r < 4; r++) {
      float bs[4] = {0.f, 0.f, 0.f, 0.f}, bd[4] = {0.f, 0.f, 0.f, 0.f};
      #pragma unroll
      for (int c = 0; c < CT; c++) {
        int hd = c / FPH;
        bs[hd] += acc[c][r] * aS[c];
        bd[hd] += acc[c][r] * aD[c];
      }
      #pragma unroll
      for (int off = 1; off < 16; off <<= 1)
        #pragma unroll
        for (int h = 0; h < 4; h++) {
          bs[h] += __shfl_xor(bs[h], off);
          bd[h] += __shfl_xor(bd[h], off);
        }
      int row = row_base + r;
      if (m < 4 && row < NN) {
        float vs = (m == 0) ? bs[0] : (m == 1) ? bs[1] : (m == 2) ? bs[2] : bs[3];
        float vd = (m == 0) ? bd[0] : (m == 1) ? bd[1] : (m == 2) ? bd[2] : bd[3];
        as_out[row * 4 + m] = vs;
        ad_out[row * 4 + m] = vd;
      }
    }
  }
}

// ---------------- merged front kernel: gemm1 | scatter | pack(W2..Wf1) ------
// gemm1 blocks come FIRST so MFMA work starts immediately; the latency-bound
// scatter blocks fill in around it. Self-loops are implicit (slot 0 == dst),
// so the scatter only covers the NE real edges, 4 per thread for ILP.

__global__ __launch_bounds__(256) void front_kernel(
    const int* __restrict__ edge_src, const int* __restrict__ edge_dst,
    int* __restrict__ count, int* __restrict__ csr_src,
    const float* __restrict__ W1,
    const float* __restrict__ W2, __half* __restrict__ Wp2,
    const float* __restrict__ W3, __half* __restrict__ Wp3,
    const float* __restrict__ W4, __half* __restrict__ Wp4,
    const float* __restrict__ Wr, __half* __restrict__ Wrp,
    const float* __restrict__ Wf1, __half* __restrict__ Wf1p,
    const float* __restrict__ x, __half* __restrict__ Ch,
    const float* __restrict__ a_src, const float* __restrict__ a_dst,
    float* __restrict__ as_out, float* __restrict__ ad_out) {
  int b = blockIdx.x;
  if (b >= NT) {
    int b2 = b - NT;
    if (b2 < SCAT2_B) {
      int e0 = (b2 * 256 + threadIdx.x) * 4;
      if (e0 < NE) {                       // NE % 4 == 0: quad never straddles
        int4 s4 = *(const int4*)(edge_src + e0);
        int4 d4 = *(const int4*)(edge_dst + e0);
        int p0 = atomicAdd(&count[d4.x], 1);
        int p1 = atomicAdd(&count[d4.y], 1);
        int p2 = atomicAdd(&count[d4.z], 1);
        int p3 = atomicAdd(&count[d4.w], 1);
        if (p0 < CAP - 1) csr_src[d4.x * CAP + p0] = s4.x;
        if (p1 < CAP - 1) csr_src[d4.y * CAP + p1] = s4.y;
        if (p2 < CAP - 1) csr_src[d4.z * CAP + p2] = s4.z;
        if (p3 < CAP - 1) csr_src[d4.w * CAP + p3] = s4.w;
      }
      return;
    }
    int tid = (b2 - SCAT2_B) * 256 + threadIdx.x;
    if (tid < 256)            pack_w_one(W2, Wp2, 64,  tid,        256);
    else if (tid < 1280)      pack_w_one(W3, Wp3, 128, tid - 256,  1024);
    else if (tid < 5376)      pack_w_one(W4, Wp4, 256, tid - 1280, 4096);
    else if (tid < 6400)      pack_w_one(Wr, Wrp, 32,  tid - 5376, 1024);
    else if (tid < 6656)      pack_w_one(Wf1, Wf1p, 64, tid - 6400, 256);
    return;
  }

  // ---- gemm1: x[NN,128] @ W1[128,32] -> Ch fp16, + alpha epilogue ----
  constexpr int M = 32, K = 128, CT = 2, KC = 4;
  __shared__ _Float16 Ah[64 * 40];
  __shared__ _Float16 Bs[KC * CT * 64 * 8];   // 4096 halves = 8 KB
  int t = threadIdx.x;
  int w = t >> 6, l = t & 63;
  int m = l & 15, q = l >> 4;
  int row0 = b * 64;

  // pack W1 into LDS B-fragment layout (each thread: 2 frag-lane units)
  #pragma unroll
  for (int u0 = 0; u0 < 2; u0++) {
    int u = t + u0 * 256;            // 512 units total
    int ul = u & 63;
    int uc = (u >> 6) & 1;
    int ukc = u >> 7;
    int un = ul & 15, uq = ul >> 4;
    const float* src = W1 + (size_t)(ukc * 32 + uq * 8) * M + uc * 16 + un;
    _Float16* dst = &Bs[u * 8];
    #pragma unroll
    for (int j = 0; j < 8; j++) dst[j] = (_Float16)src[j * M];
  }

  f32x4_t acc[CT];
  #pragma unroll
  for (int c = 0; c < CT; c++) acc[c] = (f32x4_t){0.f, 0.f, 0.f, 0.f};

  for (int kc = 0; kc < KC; kc++) {
    __syncthreads();
    #pragma unroll
    for (int i = 0; i < 2; i++) {
      int idx = t + 256 * i;
      int row = idx >> 3, c4 = idx & 7;
      int gr = row0 + row; if (gr >= NN) gr = NN - 1;
      float4 v = *(const float4*)(x + (size_t)gr * K + kc * 32 + c4 * 4);
      _Float16 h4[4] = {(_Float16)v.x, (_Float16)v.y, (_Float16)v.z, (_Float16)v.w};
      *(uint2*)(&Ah[row * 40 + c4 * 4]) = *(const uint2*)h4;
    }
    __syncthreads();
    half8_t a = *(const half8_t*)(&Ah[(w * 16 + m) * 40 + q * 8]);
    #pragma unroll
    for (int c = 0; c < CT; c++) {
      half8_t bf = *(const half8_t*)(&Bs[((kc * CT + c) * 64 + l) * 8]);
      acc[c] = __builtin_amdgcn_mfma_f32_16x16x32_f16(a, bf, acc[c], 0, 0, 0);
    }
  }

  #pragma unroll
  for (int r = 0; r < 4; r++) {
    int row = row0 + w * 16 + q * 4 + r;
    if (row < NN) {
      #pragma unroll
      for (int c = 0; c < CT; c++)
        Ch[(size_t)row * M + c * 16 + m] = __float2half_rn(acc[c][r]);
    }
  }
  alpha_epilogue<M, 8, CT>(acc, a_src, a_dst, row0 + w * 16 + q * 4, m, as_out, ad_out);
}

// ---------------- MFMA GEMM (fp16 A) + fused alpha ----------

template<int M, int K, int C>
__global__ __launch_bounds__(256) void gemm_mfma_f16_kernel(const __half* __restrict__ A,
    const __half* __restrict__ Wp, __half* __restrict__ Ch,
    const float* __restrict__ a_src, const float* __restrict__ a_dst,
    float* __restrict__ as_out, float* __restrict__ ad_out) {
  constexpr int CT = M / 16;
  constexpr int KC = K / 32;
  __shared__ _Float16 Ah[64 * 40];
  int t = threadIdx.x;
  int w = t >> 6, l = t & 63;
  int m = l & 15, q = l >> 4;
  int row0 = blockIdx.x * 64;

  f32x4_t acc[CT];
  #pragma unroll
  for (int c = 0; c < CT; c++) acc[c] = (f32x4_t){0.f, 0.f, 0.f, 0.f};

  const half8_t* Bfrag = (const half8_t*)Wp;

  for (int kc = 0; kc < KC; kc++) {
    __syncthreads();
    {
      int row = t >> 2, c8 = t & 3;
      int gr = row0 + row; if (gr >= NN) gr = NN - 1;
      uint4 v = *(const uint4*)(A + (size_t)gr * K + kc * 32 + c8 * 8);
      *(uint4*)(&Ah[row * 40 + c8 * 8]) = v;
    }
    __syncthreads();
    half8_t a = *(const half8_t*)(&Ah[(w * 16 + m) * 40 + q * 8]);
    #pragma unroll
    for (int c = 0; c < CT; c++) {
      half8_t b = Bfrag[(kc * CT + c) * 64 + l];
      acc[c] = __builtin_amdgcn_mfma_f32_16x16x32_f16(a, b, acc[c], 0, 0, 0);
    }
  }

  #pragma unroll
  for (int r = 0; r < 4; r++) {
    int row = row0 + w * 16 + q * 4 + r;
    if (row < NN) {
      #pragma unroll
      for (int c = 0; c < CT; c++)
        Ch[(size_t)row * M + c * 16 + m] = __float2half_rn(acc[c][r]);
    }
  }
  alpha_epilogue<M, C, CT>(acc, a_src, a_dst, row0 + w * 16 + q * 4, m, as_out, ad_out);
}

// ---------------- aggregation: one wave per dst node (bucket CSR) ----------
// Slot 0 of every bucket is the implicit self-loop (src = dst); csr_src holds
// the real edges shifted by one. Loop structure is the round-0 proven pipelined
// form; the ONLY change vs round 3 is the MAC: 8x v_fma_mix_f32 (cvt+fma fused,
// bit-identical) replacing 8 cvt + 8 fma.

template<int HC, int C>
__global__ __launch_bounds__(256) void agg_kernel(const __half* __restrict__ h,
    const float* __restrict__ as_v, const float* __restrict__ ad_v,
    const int* __restrict__ count, const int* __restrict__ csr_src,
    const float* __restrict__ bias, __half* __restrict__ out) {
  constexpr int V = HC / 8;
  constexpr int G = 64 / V;
  constexpr int P = 4;
  __shared__ float4 see4[4][CAP];
  __shared__ int    ssrc[4][CAP];
  int wid = threadIdx.x >> 6, lane = threadIdx.x & 63;
  int dst = blockIdx.x * 4 + wid;          // grid is exactly NN/4
  int base = dst * CAP;
  int degE = count[dst]; if (degE > CAP - 1) degE = CAP - 1;
  int deg = degE + 1;                      // + implicit self-loop at slot 0
  float4 ad = *(const float4*)(ad_v + dst * 4);

  float d0 = 0.f, d1 = 0.f, d2 = 0.f, d3 = 0.f;
  #pragma unroll
  for (int it = 0; it < 2; it++) {
    int j = lane + it * 64;
    if (j < deg) {
      int s = (j == 0) ? dst : csr_src[base + j - 1];
      float4 as = *(const float4*)(as_v + s * 4);
      float4 x = make_float4(__expf(lrelu02(as.x + ad.x)), __expf(lrelu02(as.y + ad.y)),
                             __expf(lrelu02(as.z + ad.z)), __expf(lrelu02(as.w + ad.w)));
      ssrc[wid][j] = s; see4[wid][j] = x;
      d0 += x.x; d1 += x.y; d2 += x.z; d3 += x.w;
    }
  }
  #pragma unroll
  for (int off = 32; off > 0; off >>= 1) {
    d0 += __shfl_xor(d0, off); d1 += __shfl_xor(d1, off);
    d2 += __shfl_xor(d2, off); d3 += __shfl_xor(d3, off);
  }
  float4 inv = make_float4(1.f / d0, 1.f / d1, 1.f / d2, 1.f / d3);

  int g = lane / V, v = lane % V;
  int hd = (v * 8) / C;
  float invh = pick4(inv, hd);
  int steps = (deg + G - 1) / G;
  const uint4* hrows = (const uint4*)h;

  float px[P];
  uint4 hv[P];
  #pragma unroll
  for (int k = 0; k < P; k++) {
    int jj = k * G + g;
    bool ok = jj < deg;
    int jc = ok ? jj : 0;
    int s = ssrc[wid][jc];
    float x = ((const float*)&see4[wid][jc])[hd];
    px[k] = ok ? x * invh : 0.f;
    hv[k] = hrows[(size_t)s * V + v];
  }

  float acc[8];
  #pragma unroll
  for (int i = 0; i < 8; i++) acc[i] = 0.f;
  int nB = (steps + P - 1) / P;            // >= 1
  for (int b = 1; b <= nB; b++) {
    #pragma unroll
    for (int k = 0; k < P; k++) {
      uint4 u = hv[k];
      float p = px[k];
      FMAMIX_LO(acc[0], p, u.x); FMAMIX_HI(acc[1], p, u.x);
      FMAMIX_LO(acc[2], p, u.y); FMAMIX_HI(acc[3], p, u.y);
      FMAMIX_LO(acc[4], p, u.z); FMAMIX_HI(acc[5], p, u.z);
      FMAMIX_LO(acc[6], p, u.w); FMAMIX_HI(acc[7], p, u.w);
      int jj = (b * P + k) * G + g;
      bool ok = jj < deg;
      int jc = ok ? jj : 0;
      int s = ssrc[wid][jc];
      float x = ((const float*)&see4[wid][jc])[hd];
      px[k] = ok ? x * invh : 0.f;
      hv[k] = hrows[(size_t)s * V + v];
    }
  }

  #pragma unroll
  for (int off = V; off < 64; off <<= 1)
    #pragma unroll
    for (int i = 0; i < 8; i++) acc[i] += __shfl_xor(acc[i], off);

  if (lane < V) {
    const float4* b4 = (const float4*)bias;
    float4 ba = b4[2 * v], bb = b4[2 * v + 1];
    _Float16 o[8];
    o[0] = (_Float16)eluf(acc[0] + ba.x); o[1] = (_Float16)eluf(acc[1] + ba.y);
    o[2] = (_Float16)eluf(acc[2] + ba.z); o[3] = (_Float16)eluf(acc[3] + ba.w);
    o[4] = (_Float16)eluf(acc[4] + bb.x); o[5] = (_Float16)eluf(acc[5] + bb.y);
    o[6] = (_Float16)eluf(acc[6] + bb.z); o[7] = (_Float16)eluf(acc[7] + bb.w);
    *(uint4*)(out + (size_t)dst * HC + v * 8) = *(const uint4*)o;
  }
}

// ---------------- MFMA MLP head: 256 -> 32 -> 64 -> 1 ----------------

__global__ __launch_bounds__(256) void mlp_mfma_kernel(const __half* __restrict__ h4,
    const __half* __restrict__ Wrp, const float* __restrict__ br,
    const __half* __restrict__ Wf1p, const float* __restrict__ bf1,
    const float* __restrict__ Wf2, const float* __restrict__ bf2,
    float* __restrict__ out) {
  __shared__ _Float16 rS[64 * 40];
  int t = threadIdx.x;
  int w = t >> 6, l = t & 63;
  int m = l & 15, q = l >> 4;
  int row0 = blockIdx.x * 64;
  const half8_t* Bwr  = (const half8_t*)Wrp;
  const half8_t* Bwf1 = (const half8_t*)Wf1p;

  int arow = row0 + w * 16 + m; if (arow >= NN) arow = NN - 1;
  const half8_t* Arow = (const half8_t*)(h4 + (size_t)arow * 256);
  half8_t afr[8];
  #pragma unroll
  for (int kc = 0; kc < 8; kc++) afr[kc] = Arow[kc * 4 + q];
  f32x4_t acc1[2];
  acc1[0] = (f32x4_t){0.f, 0.f, 0.f, 0.f};
  acc1[1] = (f32x4_t){0.f, 0.f, 0.f, 0.f};
  #pragma unroll
  for (int kc = 0; kc < 8; kc++) {
    acc1[0] = __builtin_amdgcn_mfma_f32_16x16x32_f16(afr[kc], Bwr[(kc * 2 + 0) * 64 + l], acc1[0], 0, 0, 0);
    acc1[1] = __builtin_amdgcn_mfma_f32_16x16x32_f16(afr[kc], Bwr[(kc * 2 + 1) * 64 + l], acc1[1], 0, 0, 0);
  }
  #pragma unroll
  for (int c = 0; c < 2; c++)
    #pragma unroll
    for (int r = 0; r < 4; r++) {
      float vv = eluf(acc1[c][r] + br[c * 16 + m]);
      rS[(w * 16 + q * 4 + r) * 40 + c * 16 + m] = (_Float16)vv;
    }
  __syncthreads();

  half8_t a2 = *(const half8_t*)(&rS[(w * 16 + m) * 40 + q * 8]);
  f32x4_t acc2[4];
  #pragma unroll
  for (int c = 0; c < 4; c++) acc2[c] = (f32x4_t){0.f, 0.f, 0.f, 0.f};
  #pragma unroll
  for (int c = 0; c < 4; c++)
    acc2[c] = __builtin_amdgcn_mfma_f32_16x16x32_f16(a2, Bwf1[c * 64 + l], acc2[c], 0, 0, 0);

  float wv[4] = {Wf2[m], Wf2[16 + m], Wf2[32 + m], Wf2[48 + m]};
  float rsum[4];
  #pragma unroll
  for (int r = 0; r < 4; r++) {
    float sr = 0.f;
    #pragma unroll
    for (int c = 0; c < 4; c++)
      sr += eluf(acc2[c][r] + bf1[c * 16 + m]) * wv[c];
    #pragma unroll
    for (int off = 1; off < 16; off <<= 1) sr += __shfl_xor(sr, off);
    rsum[r] = sr;
  }
  if (m == 0) {
    float b = bf2[0];
    #pragma unroll
    for (int r = 0; r < 4; r++) {
      int row = row0 + w * 16 + q * 4 + r;
      if (row < NN) out[row] = rsum[r] + b;
    }
  }
}

// ---------------- launcher ----------------

extern "C" void kernel_launch(void* const* d_in, const int* in_sizes, int n_in,
                              void* d_out, int out_size, void* d_ws, size_t ws_size,
                              hipStream_t stream) {
  const float* x   = (const float*)d_in[0];
  const int*   ei  = (const int*)d_in[1];
  const float* W1  = (const float*)d_in[3];
  const float* as1 = (const float*)d_in[4];
  const float* ad1 = (const float*)d_in[5];
  const float* b1  = (const float*)d_in[6];
  const float* W2  = (const float*)d_in[7];
  const float* as2 = (const float*)d_in[8];
  const float* ad2 = (const float*)d_in[9];
  const float* b2  = (const float*)d_in[10];
  const float* W3  = (const float*)d_in[11];
  const float* as3 = (const float*)d_in[12];
  const float* ad3 = (const float*)d_in[13];
  const float* b3  = (const float*)d_in[14];
  const float* W4  = (const float*)d_in[15];
  const float* as4 = (const float*)d_in[16];
  const float* ad4 = (const float*)d_in[17];
  const float* b4  = (const float*)d_in[18];
  const float* Wr  = (const float*)d_in[19];
  const float* br  = (const float*)d_in[20];
  const float* Wf1 = (const float*)d_in[21];
  const float* bf1 = (const float*)d_in[22];
  const float* Wf2 = (const float*)d_in[23];
  const float* bf2 = (const float*)d_in[24];
  float* out = (float*)d_out;

  char* p = (char*)d_ws;
  auto alloc = [&](size_t bytes) {
    char* q = p;
    p += (bytes + 255) & ~(size_t)255;
    return q;
  };
  int* count   = (int*)alloc((size_t)NN * 4);
  int* csr_src = (int*)alloc((size_t)NN * CAP * 4);
  __half* Hh = (__half*)alloc((size_t)NN * 256 * 2);  // fp16 h (gather payload)
  __half* B2 = (__half*)alloc((size_t)NN * 128 * 2);  // agg out (layers 1/3)
  __half* B3 = (__half*)alloc((size_t)NN * 256 * 2);  // agg out (layers 2/4)
  float* as_buf = (float*)alloc((size_t)NN * 4 * 4);
  float* ad_buf = (float*)alloc((size_t)NN * 4 * 4);
  __half* Wp2 = (__half*)alloc((size_t)32 * 64 * 2);
  __half* Wp3 = (__half*)alloc((size_t)64 * 128 * 2);
  __half* Wp4 = (__half*)alloc((size_t)128 * 256 * 2);
  __half* Wrp = (__half*)alloc((size_t)256 * 32 * 2);
  __half* Wf1p = (__half*)alloc((size_t)32 * 64 * 2);

  const int* edge_src = ei;
  const int* edge_dst = ei + NE;

  hipMemsetAsync(count, 0, (size_t)NN * 4, stream);
  // gemm1 (+alpha1) | scatter | pack in one kernel — independent block ranges
  front_kernel<<<NT + SCAT2_B + PACK_B, 256, 0, stream>>>(
      edge_src, edge_dst, count, csr_src,
      W1, W2, Wp2, W3, Wp3, W4, Wp4, Wr, Wrp, Wf1, Wf1p,
      x, Hh, as1, ad1, as_buf, ad_buf);

  int gb  = NT;
  int ggb = NN / 4;   // NN % 4 == 0

  agg_kernel<32, 8><<<ggb, 256, 0, stream>>>(Hh, as_buf, ad_buf, count, csr_src, b1, B2);

  gemm_mfma_f16_kernel<64, 32, 16><<<gb, 256, 0, stream>>>(B2, Wp2, Hh, as2, ad2, as_buf, ad_buf);
  agg_kernel<64, 16><<<ggb, 256, 0, stream>>>(Hh, as_buf, ad_buf, count, csr_src, b2, B3);

  gemm_mfma_f16_kernel<128, 64, 32><<<gb, 256, 0, stream>>>(B3, Wp3, Hh, as3, ad3, as_buf, ad_buf);
  agg_kernel<128, 32><<<ggb, 256, 0, stream>>>(Hh, as_buf, ad_buf, count, csr_src, b3, B2);

  gemm_mfma_f16_kernel<256, 128, 64><<<gb, 256, 0, stream>>>(B2, Wp4, Hh, as4, ad4, as_buf, ad_buf);
  agg_kernel<256, 64><<<ggb, 256, 0, stream>>>(Hh, as_buf, ad_buf, count, csr_src, b4, B3);

  mlp_mfma_kernel<<<gb, 256, 0, stream>>>(B3, Wrp, br, Wf1p, bf1, Wf2, bf2, out);
}

// Round 5
// 381.858 us; speedup vs baseline: 1.2741x; 1.0083x over previous
//
#include <hip/hip_runtime.h>
#include <hip/hip_fp16.h>
#include <math.h>

constexpr int NN = 50000;
constexpr int NE = 800000;
constexpr int NEP = NE + NN;             // edges + self-loops
constexpr int CAP = 96;                  // bucket capacity (slot 0 = implicit self-loop)
constexpr int SCAT_B = (NE / 8 + 255) / 256;   // 391 blocks, 8 edges/thread
constexpr int PACK_B = 26;                     // 6656 pack threads (W2..Wf1)
constexpr int NT = (NN + 63) / 64;             // 782 gemm tiles

typedef _Float16 half8_t __attribute__((ext_vector_type(8)));
typedef float    f32x4_t __attribute__((ext_vector_type(4)));

__device__ __forceinline__ float lrelu02(float x) { return x > 0.f ? x : 0.2f * x; }
__device__ __forceinline__ float eluf(float x)    { return x > 0.f ? x : (__expf(x) - 1.f); }
__device__ __forceinline__ float pick4(float4 q, int hd) {
  return (hd == 0) ? q.x : (hd == 1) ? q.y : (hd == 2) ? q.z : q.w;
}

// v_fma_mix_f32: acc(f32) += p(f32) * fp16-half of u — cvt+fma in ONE VALU op.
#define FMAMIX_LO(accv, pv, uv) \
  asm("v_fma_mix_f32 %0, %1, %2, %0 op_sel:[0,0,0] op_sel_hi:[0,1,0]" \
      : "+v"(accv) : "v"(pv), "v"(uv))
#define FMAMIX_HI(accv, pv, uv) \
  asm("v_fma_mix_f32 %0, %1, %2, %0 op_sel:[0,1,0] op_sel_hi:[0,1,0]" \
      : "+v"(accv) : "v"(pv), "v"(uv))

// ---------------- W pre-pack into MFMA B-fragment order ----------------

__device__ __forceinline__ void pack_w_one(const float* __restrict__ W,
                                           __half* __restrict__ Wp,
                                           int M, int tid, int total) {
  if (tid >= total) return;
  int CT = M >> 4;
  int l = tid & 63;
  int c = (tid >> 6) % CT;
  int kc = (tid >> 6) / CT;
  int n = l & 15, q = l >> 4;
  __half* dst = Wp + (size_t)tid * 8;
  const float* src = W + (size_t)(kc * 32 + q * 8) * M + c * 16 + n;
  #pragma unroll
  for (int j = 0; j < 8; j++) dst[j] = __float2half_rn(src[j * M]);
}

// ---------------- fused alpha epilogue ----------

template<int M, int C, int CT>
__device__ __forceinline__ void alpha_epilogue(const f32x4_t* acc,
    const float* __restrict__ a_src, const float* __restrict__ a_dst,
    int row_base, int m, float* __restrict__ as_out, float* __restrict__ ad_out) {
  float aS[CT], aD[CT];
  #pragma unroll
  for (int c = 0; c < CT; c++) { aS[c] = a_src[c * 16 + m]; aD[c] = a_dst[c * 16 + m]; }

  if constexpr (C == 8) {
    #pragma unroll
    for (int r = 0; r < 4; r++) {
      float p0 = acc[0][r] * aS[0], p1 = acc[1][r] * aS[1];
      float q0 = acc[0][r] * aD[0], q1 = acc[1][r] * aD[1];
      #pragma unroll
      for (int off = 1; off < 8; off <<= 1) {
        p0 += __shfl_xor(p0, off); p1 += __shfl_xor(p1, off);
        q0 += __shfl_xor(q0, off); q1 += __shfl_xor(q1, off);
      }
      int row = row_base + r;
      if ((m & 7) == 0 && row < NN) {
        int hb = m >> 3;
        as_out[row * 4 + hb]     = p0;
        as_out[row * 4 + 2 + hb] = p1;
        ad_out[row * 4 + hb]     = q0;
        ad_out[row * 4 + 2 + hb] = q1;
      }
    }
  } else {
    constexpr int FPH = C / 16;
    #pragma unroll
    for (int r = 0; r < 4; r++) {
      float bs[4] = {0.f, 0.f, 0.f, 0.f}, bd[4] = {0.f, 0.f, 0.f, 0.f};
      #pragma unroll
      for (int c = 0; c < CT; c++) {
        int hd = c / FPH;
        bs[hd] += acc[c][r] * aS[c];
        bd[hd] += acc[c][r] * aD[c];
      }
      #pragma unroll
      for (int off = 1; off < 16; off <<= 1)
        #pragma unroll
        for (int h = 0; h < 4; h++) {
          bs[h] += __shfl_xor(bs[h], off);
          bd[h] += __shfl_xor(bd[h], off);
        }
      int row = row_base + r;
      if (m < 4 && row < NN) {
        float vs = (m == 0) ? bs[0] : (m == 1) ? bs[1] : (m == 2) ? bs[2] : bs[3];
        float vd = (m == 0) ? bd[0] : (m == 1) ? bd[1] : (m == 2) ? bd[2] : bd[3];
        as_out[row * 4 + m] = vs;
        ad_out[row * 4 + m] = vd;
      }
    }
  }
}

// ---------------- merged front kernel: gemm1 | scatter | pack(W2..Wf1) ------
// gemm1 blocks come FIRST so MFMA work starts immediately; the latency-bound
// scatter blocks fill in around it. Self-loops are implicit (slot 0 == dst),
// so the scatter only covers the NE real edges, 8 per thread for ILP.

__global__ __launch_bounds__(256) void front_kernel(
    const int* __restrict__ edge_src, const int* __restrict__ edge_dst,
    int* __restrict__ count, int* __restrict__ csr_src,
    const float* __restrict__ W1,
    const float* __restrict__ W2, __half* __restrict__ Wp2,
    const float* __restrict__ W3, __half* __restrict__ Wp3,
    const float* __restrict__ W4, __half* __restrict__ Wp4,
    const float* __restrict__ Wr, __half* __restrict__ Wrp,
    const float* __restrict__ Wf1, __half* __restrict__ Wf1p,
    const float* __restrict__ x, __half* __restrict__ Ch,
    const float* __restrict__ a_src, const float* __restrict__ a_dst,
    float* __restrict__ as_out, float* __restrict__ ad_out) {
  int b = blockIdx.x;
  if (b >= NT) {
    int b2 = b - NT;
    if (b2 < SCAT_B) {
      int e0 = (b2 * 256 + threadIdx.x) * 8;
      if (e0 < NE) {                       // NE % 8 == 0: octet never straddles
        int4 sa = *(const int4*)(edge_src + e0);
        int4 sb = *(const int4*)(edge_src + e0 + 4);
        int4 da = *(const int4*)(edge_dst + e0);
        int4 db = *(const int4*)(edge_dst + e0 + 4);
        int p0 = atomicAdd(&count[da.x], 1);
        int p1 = atomicAdd(&count[da.y], 1);
        int p2 = atomicAdd(&count[da.z], 1);
        int p3 = atomicAdd(&count[da.w], 1);
        int p4 = atomicAdd(&count[db.x], 1);
        int p5 = atomicAdd(&count[db.y], 1);
        int p6 = atomicAdd(&count[db.z], 1);
        int p7 = atomicAdd(&count[db.w], 1);
        if (p0 < CAP - 1) csr_src[da.x * CAP + p0] = sa.x;
        if (p1 < CAP - 1) csr_src[da.y * CAP + p1] = sa.y;
        if (p2 < CAP - 1) csr_src[da.z * CAP + p2] = sa.z;
        if (p3 < CAP - 1) csr_src[da.w * CAP + p3] = sa.w;
        if (p4 < CAP - 1) csr_src[db.x * CAP + p4] = sb.x;
        if (p5 < CAP - 1) csr_src[db.y * CAP + p5] = sb.y;
        if (p6 < CAP - 1) csr_src[db.z * CAP + p6] = sb.z;
        if (p7 < CAP - 1) csr_src[db.w * CAP + p7] = sb.w;
      }
      return;
    }
    int tid = (b2 - SCAT_B) * 256 + threadIdx.x;
    if (tid < 256)            pack_w_one(W2, Wp2, 64,  tid,        256);
    else if (tid < 1280)      pack_w_one(W3, Wp3, 128, tid - 256,  1024);
    else if (tid < 5376)      pack_w_one(W4, Wp4, 256, tid - 1280, 4096);
    else if (tid < 6400)      pack_w_one(Wr, Wrp, 32,  tid - 5376, 1024);
    else if (tid < 6656)      pack_w_one(Wf1, Wf1p, 64, tid - 6400, 256);
    return;
  }

  // ---- gemm1: x[NN,128] @ W1[128,32] -> Ch fp16, + alpha epilogue ----
  constexpr int M = 32, K = 128, CT = 2, KC = 4;
  __shared__ _Float16 Ah[64 * 40];
  __shared__ _Float16 Bs[KC * CT * 64 * 8];   // 4096 halves = 8 KB
  int t = threadIdx.x;
  int w = t >> 6, l = t & 63;
  int m = l & 15, q = l >> 4;
  int row0 = b * 64;

  // pack W1 into LDS B-fragment layout (each thread: 2 frag-lane units)
  #pragma unroll
  for (int u0 = 0; u0 < 2; u0++) {
    int u = t + u0 * 256;            // 512 units total
    int ul = u & 63;
    int uc = (u >> 6) & 1;
    int ukc = u >> 7;
    int un = ul & 15, uq = ul >> 4;
    const float* src = W1 + (size_t)(ukc * 32 + uq * 8) * M + uc * 16 + un;
    _Float16* dst = &Bs[u * 8];
    #pragma unroll
    for (int j = 0; j < 8; j++) dst[j] = (_Float16)src[j * M];
  }

  f32x4_t acc[CT];
  #pragma unroll
  for (int c = 0; c < CT; c++) acc[c] = (f32x4_t){0.f, 0.f, 0.f, 0.f};

  for (int kc = 0; kc < KC; kc++) {
    __syncthreads();
    #pragma unroll
    for (int i = 0; i < 2; i++) {
      int idx = t + 256 * i;
      int row = idx >> 3, c4 = idx & 7;
      int gr = row0 + row; if (gr >= NN) gr = NN - 1;
      float4 v = *(const float4*)(x + (size_t)gr * K + kc * 32 + c4 * 4);
      _Float16 h4[4] = {(_Float16)v.x, (_Float16)v.y, (_Float16)v.z, (_Float16)v.w};
      *(uint2*)(&Ah[row * 40 + c4 * 4]) = *(const uint2*)h4;
    }
    __syncthreads();
    half8_t a = *(const half8_t*)(&Ah[(w * 16 + m) * 40 + q * 8]);
    #pragma unroll
    for (int c = 0; c < CT; c++) {
      half8_t bf = *(const half8_t*)(&Bs[((kc * CT + c) * 64 + l) * 8]);
      acc[c] = __builtin_amdgcn_mfma_f32_16x16x32_f16(a, bf, acc[c], 0, 0, 0);
    }
  }

  #pragma unroll
  for (int r = 0; r < 4; r++) {
    int row = row0 + w * 16 + q * 4 + r;
    if (row < NN) {
      #pragma unroll
      for (int c = 0; c < CT; c++)
        Ch[(size_t)row * M + c * 16 + m] = __float2half_rn(acc[c][r]);
    }
  }
  alpha_epilogue<M, 8, CT>(acc, a_src, a_dst, row0 + w * 16 + q * 4, m, as_out, ad_out);
}

// ---------------- MFMA GEMM (fp16 A) + fused alpha ----------

template<int M, int K, int C>
__global__ __launch_bounds__(256) void gemm_mfma_f16_kernel(const __half* __restrict__ A,
    const __half* __restrict__ Wp, __half* __restrict__ Ch,
    const float* __restrict__ a_src, const float* __restrict__ a_dst,
    float* __restrict__ as_out, float* __restrict__ ad_out) {
  constexpr int CT = M / 16;
  constexpr int KC = K / 32;
  __shared__ _Float16 Ah[64 * 40];
  int t = threadIdx.x;
  int w = t >> 6, l = t & 63;
  int m = l & 15, q = l >> 4;
  int row0 = blockIdx.x * 64;

  f32x4_t acc[CT];
  #pragma unroll
  for (int c = 0; c < CT; c++) acc[c] = (f32x4_t){0.f, 0.f, 0.f, 0.f};

  const half8_t* Bfrag = (const half8_t*)Wp;

  for (int kc = 0; kc < KC; kc++) {
    __syncthreads();
    {
      int row = t >> 2, c8 = t & 3;
      int gr = row0 + row; if (gr >= NN) gr = NN - 1;
      uint4 v = *(const uint4*)(A + (size_t)gr * K + kc * 32 + c8 * 8);
      *(uint4*)(&Ah[row * 40 + c8 * 8]) = v;
    }
    __syncthreads();
    half8_t a = *(const half8_t*)(&Ah[(w * 16 + m) * 40 + q * 8]);
    #pragma unroll
    for (int c = 0; c < CT; c++) {
      half8_t b = Bfrag[(kc * CT + c) * 64 + l];
      acc[c] = __builtin_amdgcn_mfma_f32_16x16x32_f16(a, b, acc[c], 0, 0, 0);
    }
  }

  #pragma unroll
  for (int r = 0; r < 4; r++) {
    int row = row0 + w * 16 + q * 4 + r;
    if (row < NN) {
      #pragma unroll
      for (int c = 0; c < CT; c++)
        Ch[(size_t)row * M + c * 16 + m] = __float2half_rn(acc[c][r]);
    }
  }
  alpha_epilogue<M, C, CT>(acc, a_src, a_dst, row0 + w * 16 + q * 4, m, as_out, ad_out);
}

// ---------------- aggregation: one wave per dst node (bucket CSR) ----------
// Slot 0 of every bucket is the implicit self-loop (src = dst); csr_src holds
// the real edges shifted by one. Same proven pipelined loop; pipeline depth P
// raised to 6 for HC>=128 (VGPR budget stays <=64 so occupancy is unchanged)
// to carry more gathers in flight.

template<int HC, int C>
__global__ __launch_bounds__(256) void agg_kernel(const __half* __restrict__ h,
    const float* __restrict__ as_v, const float* __restrict__ ad_v,
    const int* __restrict__ count, const int* __restrict__ csr_src,
    const float* __restrict__ bias, __half* __restrict__ out) {
  constexpr int V = HC / 8;
  constexpr int G = 64 / V;
  constexpr int P = (HC >= 128) ? 6 : 4;
  __shared__ float4 see4[4][CAP];
  __shared__ int    ssrc[4][CAP];
  int wid = threadIdx.x >> 6, lane = threadIdx.x & 63;
  int dst = blockIdx.x * 4 + wid;          // grid is exactly NN/4
  int base = dst * CAP;
  int degE = count[dst]; if (degE > CAP - 1) degE = CAP - 1;
  int deg = degE + 1;                      // + implicit self-loop at slot 0
  float4 ad = *(const float4*)(ad_v + dst * 4);

  float d0 = 0.f, d1 = 0.f, d2 = 0.f, d3 = 0.f;
  #pragma unroll
  for (int it = 0; it < 2; it++) {
    int j = lane + it * 64;
    if (j < deg) {
      int s = (j == 0) ? dst : csr_src[base + j - 1];
      float4 as = *(const float4*)(as_v + s * 4);
      float4 x = make_float4(__expf(lrelu02(as.x + ad.x)), __expf(lrelu02(as.y + ad.y)),
                             __expf(lrelu02(as.z + ad.z)), __expf(lrelu02(as.w + ad.w)));
      ssrc[wid][j] = s; see4[wid][j] = x;
      d0 += x.x; d1 += x.y; d2 += x.z; d3 += x.w;
    }
  }
  #pragma unroll
  for (int off = 32; off > 0; off >>= 1) {
    d0 += __shfl_xor(d0, off); d1 += __shfl_xor(d1, off);
    d2 += __shfl_xor(d2, off); d3 += __shfl_xor(d3, off);
  }
  float4 inv = make_float4(1.f / d0, 1.f / d1, 1.f / d2, 1.f / d3);

  int g = lane / V, v = lane % V;
  int hd = (v * 8) / C;
  float invh = pick4(inv, hd);
  int steps = (deg + G - 1) / G;
  const uint4* hrows = (const uint4*)h;

  float px[P];
  uint4 hv[P];
  #pragma unroll
  for (int k = 0; k < P; k++) {
    int jj = k * G + g;
    bool ok = jj < deg;
    int jc = ok ? jj : 0;
    int s = ssrc[wid][jc];
    float x = ((const float*)&see4[wid][jc])[hd];
    px[k] = ok ? x * invh : 0.f;
    hv[k] = hrows[(size_t)s * V + v];
  }

  float acc[8];
  #pragma unroll
  for (int i = 0; i < 8; i++) acc[i] = 0.f;
  int nB = (steps + P - 1) / P;            // >= 1
  for (int b = 1; b <= nB; b++) {
    #pragma unroll
    for (int k = 0; k < P; k++) {
      uint4 u = hv[k];
      float p = px[k];
      FMAMIX_LO(acc[0], p, u.x); FMAMIX_HI(acc[1], p, u.x);
      FMAMIX_LO(acc[2], p, u.y); FMAMIX_HI(acc[3], p, u.y);
      FMAMIX_LO(acc[4], p, u.z); FMAMIX_HI(acc[5], p, u.z);
      FMAMIX_LO(acc[6], p, u.w); FMAMIX_HI(acc[7], p, u.w);
      int jj = (b * P + k) * G + g;
      bool ok = jj < deg;
      int jc = ok ? jj : 0;
      int s = ssrc[wid][jc];
      float x = ((const float*)&see4[wid][jc])[hd];
      px[k] = ok ? x * invh : 0.f;
      hv[k] = hrows[(size_t)s * V + v];
    }
  }

  #pragma unroll
  for (int off = V; off < 64; off <<= 1)
    #pragma unroll
    for (int i = 0; i < 8; i++) acc[i] += __shfl_xor(acc[i], off);

  if (lane < V) {
    const float4* b4 = (const float4*)bias;
    float4 ba = b4[2 * v], bb = b4[2 * v + 1];
    _Float16 o[8];
    o[0] = (_Float16)eluf(acc[0] + ba.x); o[1] = (_Float16)eluf(acc[1] + ba.y);
    o[2] = (_Float16)eluf(acc[2] + ba.z); o[3] = (_Float16)eluf(acc[3] + ba.w);
    o[4] = (_Float16)eluf(acc[4] + bb.x); o[5] = (_Float16)eluf(acc[5] + bb.y);
    o[6] = (_Float16)eluf(acc[6] + bb.z); o[7] = (_Float16)eluf(acc[7] + bb.w);
    *(uint4*)(out + (size_t)dst * HC + v * 8) = *(const uint4*)o;
  }
}

// ---------------- MFMA MLP head: 256 -> 32 -> 64 -> 1 ----------------

__global__ __launch_bounds__(256) void mlp_mfma_kernel(const __half* __restrict__ h4,
    const __half* __restrict__ Wrp, const float* __restrict__ br,
    const __half* __restrict__ Wf1p, const float* __restrict__ bf1,
    const float* __restrict__ Wf2, const float* __restrict__ bf2,
    float* __restrict__ out) {
  __shared__ _Float16 rS[64 * 40];
  int t = threadIdx.x;
  int w = t >> 6, l = t & 63;
  int m = l & 15, q = l >> 4;
  int row0 = blockIdx.x * 64;
  const half8_t* Bwr  = (const half8_t*)Wrp;
  const half8_t* Bwf1 = (const half8_t*)Wf1p;

  int arow = row0 + w * 16 + m; if (arow >= NN) arow = NN - 1;
  const half8_t* Arow = (const half8_t*)(h4 + (size_t)arow * 256);
  half8_t afr[8];
  #pragma unroll
  for (int kc = 0; kc < 8; kc++) afr[kc] = Arow[kc * 4 + q];
  f32x4_t acc1[2];
  acc1[0] = (f32x4_t){0.f, 0.f, 0.f, 0.f};
  acc1[1] = (f32x4_t){0.f, 0.f, 0.f, 0.f};
  #pragma unroll
  for (int kc = 0; kc < 8; kc++) {
    acc1[0] = __builtin_amdgcn_mfma_f32_16x16x32_f16(afr[kc], Bwr[(kc * 2 + 0) * 64 + l], acc1[0], 0, 0, 0);
    acc1[1] = __builtin_amdgcn_mfma_f32_16x16x32_f16(afr[kc], Bwr[(kc * 2 + 1) * 64 + l], acc1[1], 0, 0, 0);
  }
  #pragma unroll
  for (int c = 0; c < 2; c++)
    #pragma unroll
    for (int r = 0; r < 4; r++) {
      float vv = eluf(acc1[c][r] + br[c * 16 + m]);
      rS[(w * 16 + q * 4 + r) * 40 + c * 16 + m] = (_Float16)vv;
    }
  __syncthreads();

  half8_t a2 = *(const half8_t*)(&rS[(w * 16 + m) * 40 + q * 8]);
  f32x4_t acc2[4];
  #pragma unroll
  for (int c = 0; c < 4; c++) acc2[c] = (f32x4_t){0.f, 0.f, 0.f, 0.f};
  #pragma unroll
  for (int c = 0; c < 4; c++)
    acc2[c] = __builtin_amdgcn_mfma_f32_16x16x32_f16(a2, Bwf1[c * 64 + l], acc2[c], 0, 0, 0);

  float wv[4] = {Wf2[m], Wf2[16 + m], Wf2[32 + m], Wf2[48 + m]};
  float rsum[4];
  #pragma unroll
  for (int r = 0; r < 4; r++) {
    float sr = 0.f;
    #pragma unroll
    for (int c = 0; c < 4; c++)
      sr += eluf(acc2[c][r] + bf1[c * 16 + m]) * wv[c];
    #pragma unroll
    for (int off = 1; off < 16; off <<= 1) sr += __shfl_xor(sr, off);
    rsum[r] = sr;
  }
  if (m == 0) {
    float b = bf2[0];
    #pragma unroll
    for (int r = 0; r < 4; r++) {
      int row = row0 + w * 16 + q * 4 + r;
      if (row < NN) out[row] = rsum[r] + b;
    }
  }
}

// ---------------- launcher ----------------

extern "C" void kernel_launch(void* const* d_in, const int* in_sizes, int n_in,
                              void* d_out, int out_size, void* d_ws, size_t ws_size,
                              hipStream_t stream) {
  const float* x   = (const float*)d_in[0];
  const int*   ei  = (const int*)d_in[1];
  const float* W1  = (const float*)d_in[3];
  const float* as1 = (const float*)d_in[4];
  const float* ad1 = (const float*)d_in[5];
  const float* b1  = (const float*)d_in[6];
  const float* W2  = (const float*)d_in[7];
  const float* as2 = (const float*)d_in[8];
  const float* ad2 = (const float*)d_in[9];
  const float* b2  = (const float*)d_in[10];
  const float* W3  = (const float*)d_in[11];
  const float* as3 = (const float*)d_in[12];
  const float* ad3 = (const float*)d_in[13];
  const float* b3  = (const float*)d_in[14];
  const float* W4  = (const float*)d_in[15];
  const float* as4 = (const float*)d_in[16];
  const float* ad4 = (const float*)d_in[17];
  const float* b4  = (const float*)d_in[18];
  const float* Wr  = (const float*)d_in[19];
  const float* br  = (const float*)d_in[20];
  const float* Wf1 = (const float*)d_in[21];
  const float* bf1 = (const float*)d_in[22];
  const float* Wf2 = (const float*)d_in[23];
  const float* bf2 = (const float*)d_in[24];
  float* out = (float*)d_out;

  char* p = (char*)d_ws;
  auto alloc = [&](size_t bytes) {
    char* q = p;
    p += (bytes + 255) & ~(size_t)255;
    return q;
  };
  int* count   = (int*)alloc((size_t)NN * 4);
  int* csr_src = (int*)alloc((size_t)NN * CAP * 4);
  __half* Hh = (__half*)alloc((size_t)NN * 256 * 2);  // fp16 h (gather payload)
  __half* B2 = (__half*)alloc((size_t)NN * 128 * 2);  // agg out (layers 1/3)
  __half* B3 = (__half*)alloc((size_t)NN * 256 * 2);  // agg out (layers 2/4)
  float* as_buf = (float*)alloc((size_t)NN * 4 * 4);
  float* ad_buf = (float*)alloc((size_t)NN * 4 * 4);
  __half* Wp2 = (__half*)alloc((size_t)32 * 64 * 2);
  __half* Wp3 = (__half*)alloc((size_t)64 * 128 * 2);
  __half* Wp4 = (__half*)alloc((size_t)128 * 256 * 2);
  __half* Wrp = (__half*)alloc((size_t)256 * 32 * 2);
  __half* Wf1p = (__half*)alloc((size_t)32 * 64 * 2);

  const int* edge_src = ei;
  const int* edge_dst = ei + NE;

  hipMemsetAsync(count, 0, (size_t)NN * 4, stream);
  // gemm1 (+alpha1) | scatter | pack in one kernel — independent block ranges
  front_kernel<<<NT + SCAT_B + PACK_B, 256, 0, stream>>>(
      edge_src, edge_dst, count, csr_src,
      W1, W2, Wp2, W3, Wp3, W4, Wp4, Wr, Wrp, Wf1, Wf1p,
      x, Hh, as1, ad1, as_buf, ad_buf);

  int gb  = NT;
  int ggb = NN / 4;   // NN % 4 == 0

  agg_kernel<32, 8><<<ggb, 256, 0, stream>>>(Hh, as_buf, ad_buf, count, csr_src, b1, B2);

  gemm_mfma_f16_kernel<64, 32, 16><<<gb, 256, 0, stream>>>(B2, Wp2, Hh, as2, ad2, as_buf, ad_buf);
  agg_kernel<64, 16><<<ggb, 256, 0, stream>>>(Hh, as_buf, ad_buf, count, csr_src, b2, B3);

  gemm_mfma_f16_kernel<128, 64, 32><<<gb, 256, 0, stream>>>(B3, Wp3, Hh, as3, ad3, as_buf, ad_buf);
  agg_kernel<128, 32><<<ggb, 256, 0, stream>>>(Hh, as_buf, ad_buf, count, csr_src, b3, B2);

  gemm_mfma_f16_kernel<256, 128, 64><<<gb, 256, 0, stream>>>(B2, Wp4, Hh, as4, ad4, as_buf, ad_buf);
  agg_kernel<256, 64><<<ggb, 256, 0, stream>>>(Hh, as_buf, ad_buf, count, csr_src, b4, B3);

  mlp_mfma_kernel<<<gb, 256, 0, stream>>>(B3, Wrp, br, Wf1p, bf1, Wf2, bf2, out);
}

// Round 6
// 381.580 us; speedup vs baseline: 1.2751x; 1.0007x over previous
//
#include <hip/hip_runtime.h>
#include <hip/hip_fp16.h>
#include <math.h>

constexpr int NN = 50000;
constexpr int NE = 800000;
constexpr int NEP = NE + NN;             // edges + self-loops
constexpr int CAP = 96;                  // bucket capacity (slot 0 = implicit self-loop)
constexpr int SCAT_B = (NE / 8 + 255) / 256;   // 391 blocks, 8 edges/thread
constexpr int PACK_B = 26;                     // 6656 pack threads (W2..Wf1)
constexpr int NT = (NN + 63) / 64;             // 782 gemm tiles

typedef _Float16 half8_t __attribute__((ext_vector_type(8)));
typedef float    f32x4_t __attribute__((ext_vector_type(4)));
typedef unsigned int u32x4 __attribute__((ext_vector_type(4)));

__device__ __forceinline__ float lrelu02(float x) { return x > 0.f ? x : 0.2f * x; }
__device__ __forceinline__ float eluf(float x)    { return x > 0.f ? x : (__expf(x) - 1.f); }
__device__ __forceinline__ float pick4(float4 q, int hd) {
  return (hd == 0) ? q.x : (hd == 1) ? q.y : (hd == 2) ? q.z : q.w;
}

// v_fma_mix_f32: acc(f32) += p(f32) * fp16-half of u — cvt+fma in ONE VALU op.
#define FMAMIX_LO(accv, pv, uv) \
  asm("v_fma_mix_f32 %0, %1, %2, %0 op_sel:[0,0,0] op_sel_hi:[0,1,0]" \
      : "+v"(accv) : "v"(pv), "v"(uv))
#define FMAMIX_HI(accv, pv, uv) \
  asm("v_fma_mix_f32 %0, %1, %2, %0 op_sel:[0,1,0] op_sel_hi:[0,1,0]" \
      : "+v"(accv) : "v"(pv), "v"(uv))

// ---------------- W pre-pack into MFMA B-fragment order ----------------

__device__ __forceinline__ void pack_w_one(const float* __restrict__ W,
                                           __half* __restrict__ Wp,
                                           int M, int tid, int total) {
  if (tid >= total) return;
  int CT = M >> 4;
  int l = tid & 63;
  int c = (tid >> 6) % CT;
  int kc = (tid >> 6) / CT;
  int n = l & 15, q = l >> 4;
  __half* dst = Wp + (size_t)tid * 8;
  const float* src = W + (size_t)(kc * 32 + q * 8) * M + c * 16 + n;
  #pragma unroll
  for (int j = 0; j < 8; j++) dst[j] = __float2half_rn(src[j * M]);
}

// ---------------- fused alpha epilogue ----------

template<int M, int C, int CT>
__device__ __forceinline__ void alpha_epilogue(const f32x4_t* acc,
    const float* __restrict__ a_src, const float* __restrict__ a_dst,
    int row_base, int m, float* __restrict__ as_out, float* __restrict__ ad_out) {
  float aS[CT], aD[CT];
  #pragma unroll
  for (int c = 0; c < CT; c++) { aS[c] = a_src[c * 16 + m]; aD[c] = a_dst[c * 16 + m]; }

  if constexpr (C == 8) {
    #pragma unroll
    for (int r = 0; r < 4; r++) {
      float p0 = acc[0][r] * aS[0], p1 = acc[1][r] * aS[1];
      float q0 = acc[0][r] * aD[0], q1 = acc[1][r] * aD[1];
      #pragma unroll
      for (int off = 1; off < 8; off <<= 1) {
        p0 += __shfl_xor(p0, off); p1 += __shfl_xor(p1, off);
        q0 += __shfl_xor(q0, off); q1 += __shfl_xor(q1, off);
      }
      int row = row_base + r;
      if ((m & 7) == 0 && row < NN) {
        int hb = m >> 3;
        as_out[row * 4 + hb]     = p0;
        as_out[row * 4 + 2 + hb] = p1;
        ad_out[row * 4 + hb]     = q0;
        ad_out[row * 4 + 2 + hb] = q1;
      }
    }
  } else {
    constexpr int FPH = C / 16;
    #pragma unroll
    for (int r = 0; r < 4; r++) {
      float bs[4] = {0.f, 0.f, 0.f, 0.f}, bd[4] = {0.f, 0.f, 0.f, 0.f};
      #pragma unroll
      for (int c = 0; c < CT; c++) {
        int hd = c / FPH;
        bs[hd] += acc[c][r] * aS[c];
        bd[hd] += acc[c][r] * aD[c];
      }
      #pragma unroll
      for (int off = 1; off < 16; off <<= 1)
        #pragma unroll
        for (int h = 0; h < 4; h++) {
          bs[h] += __shfl_xor(bs[h], off);
          bd[h] += __shfl_xor(bd[h], off);
        }
      int row = row_base + r;
      if (m < 4 && row < NN) {
        float vs = (m == 0) ? bs[0] : (m == 1) ? bs[1] : (m == 2) ? bs[2] : bs[3];
        float vd = (m == 0) ? bd[0] : (m == 1) ? bd[1] : (m == 2) ? bd[2] : bd[3];
        as_out[row * 4 + m] = vs;
        ad_out[row * 4 + m] = vd;
      }
    }
  }
}

// ---------------- merged front kernel: gemm1 | scatter | pack(W2..Wf1) ------

__global__ __launch_bounds__(256) void front_kernel(
    const int* __restrict__ edge_src, const int* __restrict__ edge_dst,
    int* __restrict__ count, int* __restrict__ csr_src,
    const float* __restrict__ W1,
    const float* __restrict__ W2, __half* __restrict__ Wp2,
    const float* __restrict__ W3, __half* __restrict__ Wp3,
    const float* __restrict__ W4, __half* __restrict__ Wp4,
    const float* __restrict__ Wr, __half* __restrict__ Wrp,
    const float* __restrict__ Wf1, __half* __restrict__ Wf1p,
    const float* __restrict__ x, __half* __restrict__ Ch,
    const float* __restrict__ a_src, const float* __restrict__ a_dst,
    float* __restrict__ as_out, float* __restrict__ ad_out) {
  int b = blockIdx.x;
  if (b >= NT) {
    int b2 = b - NT;
    if (b2 < SCAT_B) {
      int e0 = (b2 * 256 + threadIdx.x) * 8;
      if (e0 < NE) {                       // NE % 8 == 0: octet never straddles
        int4 sa = *(const int4*)(edge_src + e0);
        int4 sb = *(const int4*)(edge_src + e0 + 4);
        int4 da = *(const int4*)(edge_dst + e0);
        int4 db = *(const int4*)(edge_dst + e0 + 4);
        int p0 = atomicAdd(&count[da.x], 1);
        int p1 = atomicAdd(&count[da.y], 1);
        int p2 = atomicAdd(&count[da.z], 1);
        int p3 = atomicAdd(&count[da.w], 1);
        int p4 = atomicAdd(&count[db.x], 1);
        int p5 = atomicAdd(&count[db.y], 1);
        int p6 = atomicAdd(&count[db.z], 1);
        int p7 = atomicAdd(&count[db.w], 1);
        if (p0 < CAP - 1) csr_src[da.x * CAP + p0] = sa.x;
        if (p1 < CAP - 1) csr_src[da.y * CAP + p1] = sa.y;
        if (p2 < CAP - 1) csr_src[da.z * CAP + p2] = sa.z;
        if (p3 < CAP - 1) csr_src[da.w * CAP + p3] = sa.w;
        if (p4 < CAP - 1) csr_src[db.x * CAP + p4] = sb.x;
        if (p5 < CAP - 1) csr_src[db.y * CAP + p5] = sb.y;
        if (p6 < CAP - 1) csr_src[db.z * CAP + p6] = sb.z;
        if (p7 < CAP - 1) csr_src[db.w * CAP + p7] = sb.w;
      }
      return;
    }
    int tid = (b2 - SCAT_B) * 256 + threadIdx.x;
    if (tid < 256)            pack_w_one(W2, Wp2, 64,  tid,        256);
    else if (tid < 1280)      pack_w_one(W3, Wp3, 128, tid - 256,  1024);
    else if (tid < 5376)      pack_w_one(W4, Wp4, 256, tid - 1280, 4096);
    else if (tid < 6400)      pack_w_one(Wr, Wrp, 32,  tid - 5376, 1024);
    else if (tid < 6656)      pack_w_one(Wf1, Wf1p, 64, tid - 6400, 256);
    return;
  }

  // ---- gemm1: x[NN,128] @ W1[128,32] -> Ch fp16, + alpha epilogue ----
  constexpr int M = 32, K = 128, CT = 2, KC = 4;
  __shared__ _Float16 Ah[64 * 40];
  __shared__ _Float16 Bs[KC * CT * 64 * 8];   // 4096 halves = 8 KB
  int t = threadIdx.x;
  int w = t >> 6, l = t & 63;
  int m = l & 15, q = l >> 4;
  int row0 = b * 64;

  #pragma unroll
  for (int u0 = 0; u0 < 2; u0++) {
    int u = t + u0 * 256;            // 512 units total
    int ul = u & 63;
    int uc = (u >> 6) & 1;
    int ukc = u >> 7;
    int un = ul & 15, uq = ul >> 4;
    const float* src = W1 + (size_t)(ukc * 32 + uq * 8) * M + uc * 16 + un;
    _Float16* dst = &Bs[u * 8];
    #pragma unroll
    for (int j = 0; j < 8; j++) dst[j] = (_Float16)src[j * M];
  }

  f32x4_t acc[CT];
  #pragma unroll
  for (int c = 0; c < CT; c++) acc[c] = (f32x4_t){0.f, 0.f, 0.f, 0.f};

  for (int kc = 0; kc < KC; kc++) {
    __syncthreads();
    #pragma unroll
    for (int i = 0; i < 2; i++) {
      int idx = t + 256 * i;
      int row = idx >> 3, c4 = idx & 7;
      int gr = row0 + row; if (gr >= NN) gr = NN - 1;
      float4 v = *(const float4*)(x + (size_t)gr * K + kc * 32 + c4 * 4);
      _Float16 h4[4] = {(_Float16)v.x, (_Float16)v.y, (_Float16)v.z, (_Float16)v.w};
      *(uint2*)(&Ah[row * 40 + c4 * 4]) = *(const uint2*)h4;
    }
    __syncthreads();
    half8_t a = *(const half8_t*)(&Ah[(w * 16 + m) * 40 + q * 8]);
    #pragma unroll
    for (int c = 0; c < CT; c++) {
      half8_t bf = *(const half8_t*)(&Bs[((kc * CT + c) * 64 + l) * 8]);
      acc[c] = __builtin_amdgcn_mfma_f32_16x16x32_f16(a, bf, acc[c], 0, 0, 0);
    }
  }

  #pragma unroll
  for (int r = 0; r < 4; r++) {
    int row = row0 + w * 16 + q * 4 + r;
    if (row < NN) {
      #pragma unroll
      for (int c = 0; c < CT; c++)
        Ch[(size_t)row * M + c * 16 + m] = __float2half_rn(acc[c][r]);
    }
  }
  alpha_epilogue<M, 8, CT>(acc, a_src, a_dst, row0 + w * 16 + q * 4, m, as_out, ad_out);
}

// ---------------- MFMA GEMM (fp16 A) + fused alpha ----------

template<int M, int K, int C>
__global__ __launch_bounds__(256) void gemm_mfma_f16_kernel(const __half* __restrict__ A,
    const __half* __restrict__ Wp, __half* __restrict__ Ch,
    const float* __restrict__ a_src, const float* __restrict__ a_dst,
    float* __restrict__ as_out, float* __restrict__ ad_out) {
  constexpr int CT = M / 16;
  constexpr int KC = K / 32;
  __shared__ _Float16 Ah[64 * 40];
  int t = threadIdx.x;
  int w = t >> 6, l = t & 63;
  int m = l & 15, q = l >> 4;
  int row0 = blockIdx.x * 64;

  f32x4_t acc[CT];
  #pragma unroll
  for (int c = 0; c < CT; c++) acc[c] = (f32x4_t){0.f, 0.f, 0.f, 0.f};

  const half8_t* Bfrag = (const half8_t*)Wp;

  for (int kc = 0; kc < KC; kc++) {
    __syncthreads();
    {
      int row = t >> 2, c8 = t & 3;
      int gr = row0 + row; if (gr >= NN) gr = NN - 1;
      uint4 v = *(const uint4*)(A + (size_t)gr * K + kc * 32 + c8 * 8);
      *(uint4*)(&Ah[row * 40 + c8 * 8]) = v;
    }
    __syncthreads();
    half8_t a = *(const half8_t*)(&Ah[(w * 16 + m) * 40 + q * 8]);
    #pragma unroll
    for (int c = 0; c < CT; c++) {
      half8_t b = Bfrag[(kc * CT + c) * 64 + l];
      acc[c] = __builtin_amdgcn_mfma_f32_16x16x32_f16(a, b, acc[c], 0, 0, 0);
    }
  }

  #pragma unroll
  for (int r = 0; r < 4; r++) {
    int row = row0 + w * 16 + q * 4 + r;
    if (row < NN) {
      #pragma unroll
      for (int c = 0; c < CT; c++)
        Ch[(size_t)row * M + c * 16 + m] = __float2half_rn(acc[c][r]);
    }
  }
  alpha_epilogue<M, C, CT>(acc, a_src, a_dst, row0 + w * 16 + q * 4, m, as_out, ad_out);
}

// ---------------- aggregation: one wave per dst node (bucket CSR) ----------
// Proven padded-pipeline loop, but gather issue/wait discipline is now
// hand-placed: inline-asm global_load_dwordx4 + counted s_waitcnt vmcnt(D-1)
// + sched_barrier (rule #18). The compiler was serializing the chain
// (VGPR=36 at P=6); this forces D loads in flight per wave.

template<int HC, int C>
__global__ __launch_bounds__(256) void agg_kernel(const __half* __restrict__ h,
    const float* __restrict__ as_v, const float* __restrict__ ad_v,
    const int* __restrict__ count, const int* __restrict__ csr_src,
    const float* __restrict__ bias, __half* __restrict__ out) {
  constexpr int V = HC / 8;
  constexpr int G = 64 / V;
  constexpr int D = (HC >= 128) ? 6 : 4;
  __shared__ float4 see4[4][CAP];
  __shared__ int    ssrc[4][CAP];
  int wid = threadIdx.x >> 6, lane = threadIdx.x & 63;
  int dst = blockIdx.x * 4 + wid;          // grid is exactly NN/4
  int base = dst * CAP;
  int degE = count[dst]; if (degE > CAP - 1) degE = CAP - 1;
  int deg = degE + 1;                      // + implicit self-loop at slot 0
  float4 ad = *(const float4*)(ad_v + dst * 4);

  float d0 = 0.f, d1 = 0.f, d2 = 0.f, d3 = 0.f;
  #pragma unroll
  for (int it = 0; it < 2; it++) {
    int j = lane + it * 64;
    if (j < deg) {
      int s = (j == 0) ? dst : csr_src[base + j - 1];
      float4 as = *(const float4*)(as_v + s * 4);
      float4 x = make_float4(__expf(lrelu02(as.x + ad.x)), __expf(lrelu02(as.y + ad.y)),
                             __expf(lrelu02(as.z + ad.z)), __expf(lrelu02(as.w + ad.w)));
      ssrc[wid][j] = s; see4[wid][j] = x;
      d0 += x.x; d1 += x.y; d2 += x.z; d3 += x.w;
    }
  }
  #pragma unroll
  for (int off = 32; off > 0; off >>= 1) {
    d0 += __shfl_xor(d0, off); d1 += __shfl_xor(d1, off);
    d2 += __shfl_xor(d2, off); d3 += __shfl_xor(d3, off);
  }
  float4 inv = make_float4(1.f / d0, 1.f / d1, 1.f / d2, 1.f / d3);

  int g = lane / V, v = lane % V;
  int hd = (v * 8) / C;
  float invh = pick4(inv, hd);
  int steps = (deg + G - 1) / G;
  const char* hb = (const char*)h;

  float px[D];
  u32x4 hv[D];

  // stage slot k with k-step j: LDS index reads + asm gather issue
  #define STAGE(kk, jexpr) { \
    int jj = (jexpr) * G + g; \
    bool okk = jj < deg; \
    int jc = okk ? jj : 0; \
    int s = ssrc[wid][jc]; \
    float xx = ((const float*)&see4[wid][jc])[hd]; \
    px[kk] = okk ? xx * invh : 0.f; \
    const void* ap = hb + (size_t)s * (HC * 2) + v * 16; \
    asm volatile("global_load_dwordx4 %0, %1, off" : "=v"(hv[kk]) : "v"(ap) : "memory"); \
  }

  #pragma unroll
  for (int k = 0; k < D; k++) STAGE(k, k)

  float acc[8];
  #pragma unroll
  for (int i = 0; i < 8; i++) acc[i] = 0.f;
  int nB = (steps + D - 1) / D;            // >= 1
  for (int b = 1; b <= nB; b++) {
    #pragma unroll
    for (int k = 0; k < D; k++) {
      if constexpr (D == 6) asm volatile("s_waitcnt vmcnt(5)" ::: "memory");
      else                  asm volatile("s_waitcnt vmcnt(3)" ::: "memory");
      __builtin_amdgcn_sched_barrier(0);
      u32x4 u = hv[k];
      float p = px[k];
      FMAMIX_LO(acc[0], p, u[0]); FMAMIX_HI(acc[1], p, u[0]);
      FMAMIX_LO(acc[2], p, u[1]); FMAMIX_HI(acc[3], p, u[1]);
      FMAMIX_LO(acc[4], p, u[2]); FMAMIX_HI(acc[5], p, u[2]);
      FMAMIX_LO(acc[6], p, u[3]); FMAMIX_HI(acc[7], p, u[3]);
      STAGE(k, b * D + k)
    }
  }
  asm volatile("s_waitcnt vmcnt(0)" ::: "memory");
  __builtin_amdgcn_sched_barrier(0);
  #undef STAGE

  #pragma unroll
  for (int off = V; off < 64; off <<= 1)
    #pragma unroll
    for (int i = 0; i < 8; i++) acc[i] += __shfl_xor(acc[i], off);

  if (lane < V) {
    const float4* b4 = (const float4*)bias;
    float4 ba = b4[2 * v], bb = b4[2 * v + 1];
    _Float16 o[8];
    o[0] = (_Float16)eluf(acc[0] + ba.x); o[1] = (_Float16)eluf(acc[1] + ba.y);
    o[2] = (_Float16)eluf(acc[2] + ba.z); o[3] = (_Float16)eluf(acc[3] + ba.w);
    o[4] = (_Float16)eluf(acc[4] + bb.x); o[5] = (_Float16)eluf(acc[5] + bb.y);
    o[6] = (_Float16)eluf(acc[6] + bb.z); o[7] = (_Float16)eluf(acc[7] + bb.w);
    *(uint4*)(out + (size_t)dst * HC + v * 8) = *(const uint4*)o;
  }
}

// ---------------- MFMA MLP head: 256 -> 32 -> 64 -> 1 ----------------

__global__ __launch_bounds__(256) void mlp_mfma_kernel(const __half* __restrict__ h4,
    const __half* __restrict__ Wrp, const float* __restrict__ br,
    const __half* __restrict__ Wf1p, const float* __restrict__ bf1,
    const float* __restrict__ Wf2, const float* __restrict__ bf2,
    float* __restrict__ out) {
  __shared__ _Float16 rS[64 * 40];
  int t = threadIdx.x;
  int w = t >> 6, l = t & 63;
  int m = l & 15, q = l >> 4;
  int row0 = blockIdx.x * 64;
  const half8_t* Bwr  = (const half8_t*)Wrp;
  const half8_t* Bwf1 = (const half8_t*)Wf1p;

  int arow = row0 + w * 16 + m; if (arow >= NN) arow = NN - 1;
  const half8_t* Arow = (const half8_t*)(h4 + (size_t)arow * 256);
  half8_t afr[8];
  #pragma unroll
  for (int kc = 0; kc < 8; kc++) afr[kc] = Arow[kc * 4 + q];
  f32x4_t acc1[2];
  acc1[0] = (f32x4_t){0.f, 0.f, 0.f, 0.f};
  acc1[1] = (f32x4_t){0.f, 0.f, 0.f, 0.f};
  #pragma unroll
  for (int kc = 0; kc < 8; kc++) {
    acc1[0] = __builtin_amdgcn_mfma_f32_16x16x32_f16(afr[kc], Bwr[(kc * 2 + 0) * 64 + l], acc1[0], 0, 0, 0);
    acc1[1] = __builtin_amdgcn_mfma_f32_16x16x32_f16(afr[kc], Bwr[(kc * 2 + 1) * 64 + l], acc1[1], 0, 0, 0);
  }
  #pragma unroll
  for (int c = 0; c < 2; c++)
    #pragma unroll
    for (int r = 0; r < 4; r++) {
      float vv = eluf(acc1[c][r] + br[c * 16 + m]);
      rS[(w * 16 + q * 4 + r) * 40 + c * 16 + m] = (_Float16)vv;
    }
  __syncthreads();

  half8_t a2 = *(const half8_t*)(&rS[(w * 16 + m) * 40 + q * 8]);
  f32x4_t acc2[4];
  #pragma unroll
  for (int c = 0; c < 4; c++) acc2[c] = (f32x4_t){0.f, 0.f, 0.f, 0.f};
  #pragma unroll
  for (int c = 0; c < 4; c++)
    acc2[c] = __builtin_amdgcn_mfma_f32_16x16x32_f16(a2, Bwf1[c * 64 + l], acc2[c], 0, 0, 0);

  float wv[4] = {Wf2[m], Wf2[16 + m], Wf2[32 + m], Wf2[48 + m]};
  float rsum[4];
  #pragma unroll
  for (int r = 0; r < 4; r++) {
    float sr = 0.f;
    #pragma unroll
    for (int c = 0; c < 4; c++)
      sr += eluf(acc2[c][r] + bf1[c * 16 + m]) * wv[c];
    #pragma unroll
    for (int off = 1; off < 16; off <<= 1) sr += __shfl_xor(sr, off);
    rsum[r] = sr;
  }
  if (m == 0) {
    float b = bf2[0];
    #pragma unroll
    for (int r = 0; r < 4; r++) {
      int row = row0 + w * 16 + q * 4 + r;
      if (row < NN) out[row] = rsum[r] + b;
    }
  }
}

// ---------------- launcher ----------------

extern "C" void kernel_launch(void* const* d_in, const int* in_sizes, int n_in,
                              void* d_out, int out_size, void* d_ws, size_t ws_size,
                              hipStream_t stream) {
  const float* x   = (const float*)d_in[0];
  const int*   ei  = (const int*)d_in[1];
  const float* W1  = (const float*)d_in[3];
  const float* as1 = (const float*)d_in[4];
  const float* ad1 = (const float*)d_in[5];
  const float* b1  = (const float*)d_in[6];
  const float* W2  = (const float*)d_in[7];
  const float* as2 = (const float*)d_in[8];
  const float* ad2 = (const float*)d_in[9];
  const float* b2  = (const float*)d_in[10];
  const float* W3  = (const float*)d_in[11];
  const float* as3 = (const float*)d_in[12];
  const float* ad3 = (const float*)d_in[13];
  const float* b3  = (const float*)d_in[14];
  const float* W4  = (const float*)d_in[15];
  const float* as4 = (const float*)d_in[16];
  const float* ad4 = (const float*)d_in[17];
  const float* b4  = (const float*)d_in[18];
  const float* Wr  = (const float*)d_in[19];
  const float* br  = (const float*)d_in[20];
  const float* Wf1 = (const float*)d_in[21];
  const float* bf1 = (const float*)d_in[22];
  const float* Wf2 = (const float*)d_in[23];
  const float* bf2 = (const float*)d_in[24];
  float* out = (float*)d_out;

  char* p = (char*)d_ws;
  auto alloc = [&](size_t bytes) {
    char* q = p;
    p += (bytes + 255) & ~(size_t)255;
    return q;
  };
  int* count   = (int*)alloc((size_t)NN * 4);
  int* csr_src = (int*)alloc((size_t)NN * CAP * 4);
  __half* Hh = (__half*)alloc((size_t)NN * 256 * 2);  // fp16 h (gather payload)
  __half* B2 = (__half*)alloc((size_t)NN * 128 * 2);  // agg out (layers 1/3)
  __half* B3 = (__half*)alloc((size_t)NN * 256 * 2);  // agg out (layers 2/4)
  float* as_buf = (float*)alloc((size_t)NN * 4 * 4);
  float* ad_buf = (float*)alloc((size_t)NN * 4 * 4);
  __half* Wp2 = (__half*)alloc((size_t)32 * 64 * 2);
  __half* Wp3 = (__half*)alloc((size_t)64 * 128 * 2);
  __half* Wp4 = (__half*)alloc((size_t)128 * 256 * 2);
  __half* Wrp = (__half*)alloc((size_t)256 * 32 * 2);
  __half* Wf1p = (__half*)alloc((size_t)32 * 64 * 2);

  const int* edge_src = ei;
  const int* edge_dst = ei + NE;

  hipMemsetAsync(count, 0, (size_t)NN * 4, stream);
  front_kernel<<<NT + SCAT_B + PACK_B, 256, 0, stream>>>(
      edge_src, edge_dst, count, csr_src,
      W1, W2, Wp2, W3, Wp3, W4, Wp4, Wr, Wrp, Wf1, Wf1p,
      x, Hh, as1, ad1, as_buf, ad_buf);

  int gb  = NT;
  int ggb = NN / 4;   // NN % 4 == 0

  agg_kernel<32, 8><<<ggb, 256, 0, stream>>>(Hh, as_buf, ad_buf, count, csr_src, b1, B2);

  gemm_mfma_f16_kernel<64, 32, 16><<<gb, 256, 0, stream>>>(B2, Wp2, Hh, as2, ad2, as_buf, ad_buf);
  agg_kernel<64, 16><<<ggb, 256, 0, stream>>>(Hh, as_buf, ad_buf, count, csr_src, b2, B3);

  gemm_mfma_f16_kernel<128, 64, 32><<<gb, 256, 0, stream>>>(B3, Wp3, Hh, as3, ad3, as_buf, ad_buf);
  agg_kernel<128, 32><<<ggb, 256, 0, stream>>>(Hh, as_buf, ad_buf, count, csr_src, b3, B2);

  gemm_mfma_f16_kernel<256, 128, 64><<<gb, 256, 0, stream>>>(B2, Wp4, Hh, as4, ad4, as_buf, ad_buf);
  agg_kernel<256, 64><<<ggb, 256, 0, stream>>>(Hh, as_buf, ad_buf, count, csr_src, b4, B3);

  mlp_mfma_kernel<<<gb, 256, 0, stream>>>(B3, Wrp, br, Wf1p, bf1, Wf2, bf2, out);
}